// Round 10
// baseline (200.159 us; speedup 1.0000x reference)
//
#include <hip/hip_runtime.h>
#include <math.h>

typedef unsigned int uint;
typedef unsigned long long ull;

#define THREADS 256
#define NC 96          // counting blocks at head of fused grid

typedef __attribute__((ext_vector_type(8))) short bf16x8;
typedef __attribute__((ext_vector_type(4))) float f32x4;

// ---- bf16 helpers (storage-only; math in fp32 / MFMA-fp32-accum) ----------
__device__ __forceinline__ float blo(uint u) { return __uint_as_float(u << 16); }
__device__ __forceinline__ float bhi(uint u) { return __uint_as_float(u & 0xffff0000u); }
__device__ __forceinline__ uint  bf16r(float x) {           // RTNE
    uint u = __float_as_uint(x);
    return (u + 0x7fffu + ((u >> 16) & 1u)) >> 16;
}
__device__ __forceinline__ uint packbf(float lo, float hi) {
    return bf16r(lo) | (bf16r(hi) << 16);
}

// ---------------------------------------------------------------------------
// K0: transpose weights to bf16 Wt[n][k] once.
// ---------------------------------------------------------------------------
__global__ __launch_bounds__(THREADS)
void transpose_w(const float* __restrict__ W_sd, const float* __restrict__ W_ds,
                 const float* __restrict__ W_l1, const float* __restrict__ W_g1,
                 ushort* __restrict__ Wt, ushort* __restrict__ Wtg1)
{
    __shared__ float tile[32][33];
    const int y = blockIdx.y;
    const float* src;
    ushort* dst;
    int dstK, kofs;
    if (y < 4) {
        src = (y == 0) ? W_sd : (y == 1) ? W_ds : (y == 2) ? W_l1 : (W_l1 + 16384);
        dst = Wt + y * 16384; dstK = 128; kofs = 0;
    } else {
        src = W_g1 + (y - 4) * 16384;
        dst = Wtg1; dstK = 256; kofs = (y - 4) * 128;
    }
    const int tix = blockIdx.x;
    const int k0 = (tix & 3) * 32, n0 = (tix >> 2) * 32;
    const int t = threadIdx.x;

    {
        const int r = t >> 3, c8 = t & 7;
        const float4 f = *(const float4*)(src + (size_t)(k0 + r) * 128 + n0 + c8 * 4);
        tile[r][c8 * 4 + 0] = f.x; tile[r][c8 * 4 + 1] = f.y;
        tile[r][c8 * 4 + 2] = f.z; tile[r][c8 * 4 + 3] = f.w;
    }
    __syncthreads();
    {
        const int n = t >> 3, k8 = t & 7;
        const float v0 = tile[k8 * 4 + 0][n], v1 = tile[k8 * 4 + 1][n];
        const float v2 = tile[k8 * 4 + 2][n], v3 = tile[k8 * 4 + 3][n];
        uint2 o; o.x = packbf(v0, v1); o.y = packbf(v2, v3);
        *(uint2*)(dst + (size_t)(n0 + n) * dstK + kofs + k0 + k8 * 4) = o;
    }
}

// ---------------------------------------------------------------------------
// shared MFMA tile body: As 64x128 bf16 (16KB), Bt 128x128 bf16 (32KB),
// XOR-swizzle kbyte ^= (row&7)<<4 on both; 4 waves x 16 rows x 128 cols.
// ---------------------------------------------------------------------------
__device__ __forceinline__ void mfma_tile_compute(const char* AsB, const char* BtB,
                                                  int wv, int ln, f32x4 acc[8])
{
    const int mrow = wv * 16 + (ln & 15);
    const int kgb  = (ln >> 4) * 16;                 // k-group byte offset
#pragma unroll
    for (int kk = 0; kk < 4; ++kk) {
        const int kbyte = kk * 64 + kgb;
        const bf16x8 a = *(const bf16x8*)(AsB + mrow * 256 + (kbyte ^ ((mrow & 7) << 4)));
#pragma unroll
        for (int tt = 0; tt < 8; ++tt) {
            const int nrow = tt * 16 + (ln & 15);
            const bf16x8 b = *(const bf16x8*)(BtB + nrow * 256 + (kbyte ^ ((nrow & 7) << 4)));
            acc[tt] = __builtin_amdgcn_mfma_f32_16x16x32_bf16(a, b, acc[tt], 0, 0, 0);
        }
    }
}

// ---------------------------------------------------------------------------
// K1 (fused, 1D grid = NC + ceil(M/64)):
//   bid < NC  -> edge counting (1 packed atomic/edge on dst) + off_out fill
//                from SORTED src (np.unique lex order). Grid-stride.
//   bid >= NC -> 64-row strip: stage A once, loop 4 weight groups
//                {stage Bt, MFMA, packed epilogue}. P[n,0:512] bf16.
// ---------------------------------------------------------------------------
__global__ __launch_bounds__(THREADS)
void gemm_node_count(const float* __restrict__ X, int M,
                     const ushort* __restrict__ Wt,
                     const float* __restrict__ b_sd, const float* __restrict__ b_ds,
                     const float* __restrict__ b_l1,
                     ushort* __restrict__ Pb,
                     const int* __restrict__ src, const int* __restrict__ dst,
                     const float* __restrict__ counts,
                     ull* __restrict__ packed_in, int* __restrict__ off_out,
                     int E)
{
    __shared__ __align__(16) char AsB[16384];
    __shared__ __align__(16) char BtB[32768];

    const int tid = threadIdx.x;
    const int bid = blockIdx.x;

    if (bid < NC) {
        const int stride = NC * THREADS;
        for (int e = bid * THREADS + tid; e < E; e += stride) {
            const int  d = dst[e];
            const uint c = (uint)counts[e];
            atomicAdd(packed_in + d, (1ULL << 32) | (ull)c);
        }
        // off_out: first edge index with src >= v (src sorted non-decreasing)
        for (int e = bid * THREADS + tid; e < E; e += stride) {
            const int cur  = src[e];
            const int prev = (e == 0) ? -1 : src[e - 1];
            for (int v = prev + 1; v <= cur; ++v) off_out[v] = e;
            if (e == E - 1)
                for (int v = cur + 1; v <= M; ++v) off_out[v] = E;
        }
        return;
    }

    const int m0 = (bid - NC) * 64;
    const int wv = tid >> 6, ln = tid & 63;

    // ---- stage A once (64 rows x 128 k, fp32 -> bf16, swizzled) ----
    {
        const int r = tid >> 2, seg = tid & 3;
        int gr = m0 + r; if (gr >= M) gr = M - 1;
        const float4* xs = (const float4*)(X + (size_t)gr * 128 + seg * 32);
#pragma unroll
        for (int i = 0; i < 4; ++i) {
            const float4 f0 = xs[i * 2], f1 = xs[i * 2 + 1];
            uint4 u;
            u.x = packbf(f0.x, f0.y); u.y = packbf(f0.z, f0.w);
            u.z = packbf(f1.x, f1.y); u.w = packbf(f1.z, f1.w);
            const int kbyte = seg * 64 + i * 16;
            *(uint4*)(AsB + r * 256 + (kbyte ^ ((r & 7) << 4))) = u;
        }
    }

    for (int grp = 0; grp < 4; ++grp) {
        // ---- stage Bt(grp) (128 n-rows x 128 k, bf16 from L2, swizzled) ----
        {
            const int rn = tid >> 1, sg = tid & 1;
            const uint4* ws = (const uint4*)(Wt + grp * 16384 + (size_t)rn * 128 + sg * 64);
#pragma unroll
            for (int i = 0; i < 8; ++i) {
                const uint4 u = ws[i];
                const int kbyte = sg * 128 + i * 16;
                *(uint4*)(BtB + rn * 256 + (kbyte ^ ((rn & 7) << 4))) = u;
            }
        }
        __syncthreads();                       // Bt (and A on first iter) ready

        f32x4 acc[8];
#pragma unroll
        for (int tt = 0; tt < 8; ++tt) acc[tt] = (f32x4){0.f, 0.f, 0.f, 0.f};
        mfma_tile_compute(AsB, BtB, wv, ln, acc);
        __syncthreads();                       // all BtB reads done

        // ---- epilogue: bias+bf16, packed uint writes (shfl-pair) ----
        const float* bias = (grp == 0) ? b_sd : (grp == 1) ? b_ds
                          : (grp == 2) ? b_l1 : nullptr;
#pragma unroll
        for (int tt = 0; tt < 8; ++tt) {
            const int n  = tt * 16 + (ln & 15);
            const float bv = bias ? bias[n] : 0.f;
#pragma unroll
            for (int r = 0; r < 4; ++r) {
                const int m = wv * 16 + ((ln >> 4) << 2) + r;
                const float val = acc[tt][r] + bv;
                const float pr  = __shfl_xor(val, 1);
                if ((ln & 1) == 0)
                    ((uint*)BtB)[m * 68 + (n >> 1)] = packbf(val, pr);
            }
        }
        __syncthreads();
        {
            const int rr = tid >> 2, sg2 = tid & 3;
            const int gr = m0 + rr;
            if (gr < M) {
                uint4* dstp = (uint4*)Pb + (size_t)gr * 64 + grp * 16 + sg2 * 4;
#pragma unroll
                for (int i = 0; i < 4; ++i)
                    dstp[i] = *(const uint4*)(BtB + rr * 272 + (sg2 * 4 + i) * 16);
            }
        }
        __syncthreads();                       // BtB free for next group
    }
}

// ---------------------------------------------------------------------------
// K2a/b/c: hierarchical exclusive scan of hi32(packed_in) -> off_in.
// ---------------------------------------------------------------------------
__global__ __launch_bounds__(256)
void scan_p1(const ull* __restrict__ packed_in, int* __restrict__ bsum, int M)
{
    __shared__ int s[256];
    const int t = threadIdx.x;
    const int i = blockIdx.x * 256 + t;
    s[t] = (i < M) ? (int)(packed_in[i] >> 32) : 0;
    __syncthreads();
#pragma unroll
    for (int o = 128; o; o >>= 1) {
        if (t < o) s[t] += s[t + o];
        __syncthreads();
    }
    if (t == 0) bsum[blockIdx.x] = s[0];
}

__global__ __launch_bounds__(1024)
void scan_p2(int* __restrict__ bsum, int NB)
{
    __shared__ int s[1024];
    const int t = threadIdx.x;
    const int v = (t < NB) ? bsum[t] : 0;
    s[t] = v;
    __syncthreads();
    for (int o = 1; o < 1024; o <<= 1) {
        const int u = (t >= o) ? s[t - o] : 0;
        __syncthreads();
        s[t] += u;
        __syncthreads();
    }
    if (t < NB) bsum[t] = s[t] - v;   // exclusive
}

__global__ __launch_bounds__(256)
void scan_p3(const ull* __restrict__ packed_in, const int* __restrict__ bsum,
             int* __restrict__ off_in, int M)
{
    __shared__ int s[256];
    const int t = threadIdx.x;
    const int i = blockIdx.x * 256 + t;
    const int v = (i < M) ? (int)(packed_in[i] >> 32) : 0;
    s[t] = v;
    __syncthreads();
    for (int o = 1; o < 256; o <<= 1) {
        const int u = (t >= o) ? s[t - o] : 0;
        __syncthreads();
        s[t] += u;
        __syncthreads();
    }
    if (i < M) off_in[i] = bsum[blockIdx.x] + s[t] - v;
}

// ---------------------------------------------------------------------------
// K3: edge_out — 1 wave per src node (sorted-src run). a[v] in registers;
//     per edge: gather bb[d] + p_ds[d], lcs in 16-lane groups (4 edges in
//     flight), fill in-CSR slot (u=v, w), accumulate h_out. Writes
//     normalized h_out -> Hout[v] (separate buffer: bb slots of OTHER rows
//     are still being read by other blocks -> cannot overwrite Pb).
// ---------------------------------------------------------------------------
__global__ __launch_bounds__(THREADS)
void edge_out(const ushort* __restrict__ Pb, ushort* __restrict__ Hout,
              const int* __restrict__ dst, const float* __restrict__ counts,
              const float* __restrict__ W_l2, const float* __restrict__ b_l2,
              const int* __restrict__ off_out,
              const int* __restrict__ off_in, int* __restrict__ cur_in,
              float2* __restrict__ uw_in, int M)
{
    const int lane = threadIdx.x & 63;
    const int wid  = threadIdx.x >> 6;
    const int v    = blockIdx.x * 4 + wid;
    if (v >= M) return;
    const int g  = lane >> 4;       // edge group 0..3
    const int gl = lane & 15;       // 8 elems per lane

    const uint* rs = (const uint*)Pb + (size_t)v * 256;
    const uint4 av = ((const uint4*)(rs + 128))[gl];       // a[v], elems 256..383
    const float4 wa = ((const float4*)W_l2)[gl * 2];
    const float4 wb = ((const float4*)W_l2)[gl * 2 + 1];
    const float bl2 = b_l2[0];

    const int base = off_out[v];
    const int end  = off_out[v + 1];

    float a0 = 0.f, a1 = 0.f, a2 = 0.f, a3 = 0.f;
    float a4 = 0.f, a5 = 0.f, a6 = 0.f, a7 = 0.f;
    float dg = 0.f;

    for (int j = base + g; j < end; j += 4) {
        const int   d = dst[j];
        const float c = counts[j];
        const uint* rd = (const uint*)Pb + (size_t)d * 256;
        const uint4 bv = ((const uint4*)(rd + 192))[gl];   // bb[d], elems 384..511
        const uint4 pv = ((const uint4*)(rd + 64))[gl];    // p_ds[d], elems 128..255

        float part =
            fmaxf(blo(av.x) + blo(bv.x), 0.f) * wa.x + fmaxf(bhi(av.x) + bhi(bv.x), 0.f) * wa.y +
            fmaxf(blo(av.y) + blo(bv.y), 0.f) * wa.z + fmaxf(bhi(av.y) + bhi(bv.y), 0.f) * wa.w +
            fmaxf(blo(av.z) + blo(bv.z), 0.f) * wb.x + fmaxf(bhi(av.z) + bhi(bv.z), 0.f) * wb.y +
            fmaxf(blo(av.w) + blo(bv.w), 0.f) * wb.z + fmaxf(bhi(av.w) + bhi(bv.w), 0.f) * wb.w;
        part += __shfl_xor(part, 1);
        part += __shfl_xor(part, 2);
        part += __shfl_xor(part, 4);
        part += __shfl_xor(part, 8);

        const float w = (1.f / (1.f + expf(-(part + bl2)))) * c;

        a0 = fmaf(blo(pv.x), w, a0); a1 = fmaf(bhi(pv.x), w, a1);
        a2 = fmaf(blo(pv.y), w, a2); a3 = fmaf(bhi(pv.y), w, a3);
        a4 = fmaf(blo(pv.z), w, a4); a5 = fmaf(bhi(pv.z), w, a5);
        a6 = fmaf(blo(pv.w), w, a6); a7 = fmaf(bhi(pv.w), w, a7);
        dg += c;

        if (gl == 0) {
            const int r1 = atomicAdd(cur_in + d, 1);
            uw_in[off_in[d] + r1] = make_float2(__int_as_float(v), w);
        }
    }

#define RED2(a) a += __shfl_xor(a, 16); a += __shfl_xor(a, 32);
    RED2(a0) RED2(a1) RED2(a2) RED2(a3) RED2(a4) RED2(a5) RED2(a6) RED2(a7) RED2(dg)
#undef RED2

    if (g == 0) {
        const float r = 1.f / fmaxf(dg, 1.f);
        uint4 o;
        o.x = packbf(a0 * r, a1 * r);
        o.y = packbf(a2 * r, a3 * r);
        o.z = packbf(a4 * r, a5 * r);
        o.w = packbf(a6 * r, a7 * r);
        ((uint4*)((uint*)Hout + (size_t)v * 64))[gl] = o;
    }
}

// ---------------------------------------------------------------------------
// K4: agg_in — 1 wave per node, in-direction only: walk uw_in CSR, gather
//     p_sd rows, normalize by deg (lo32 of packed). Writes h_in -> Pb elems
//     256..383 (a is dead after edge_out).
// ---------------------------------------------------------------------------
__global__ __launch_bounds__(THREADS)
void agg_in(ushort* __restrict__ Pb,
            const float2* __restrict__ uw_in,
            const int* __restrict__ off_in, const ull* __restrict__ packed_in,
            int M)
{
    const int lane = threadIdx.x & 63;
    const int wid  = threadIdx.x >> 6;
    const int v    = blockIdx.x * 4 + wid;
    if (v >= M) return;
    const int g  = lane >> 4;
    const int gl = lane & 15;

    const ull pk = packed_in[v];
    const int n  = (int)(pk >> 32);
    const float dg = (float)(uint)(pk & 0xffffffffu);
    const float2* __restrict__ uw = uw_in + off_in[v];

    float a0 = 0.f, a1 = 0.f, a2 = 0.f, a3 = 0.f;
    float a4 = 0.f, a5 = 0.f, a6 = 0.f, a7 = 0.f;
    for (int j = g; j < n; j += 4) {
        const float2 p = uw[j];
        const int    u = __float_as_int(p.x);
        const float  w = p.y;
        const uint4 pv = ((const uint4*)((const uint*)Pb + (size_t)u * 256))[gl];
        a0 = fmaf(blo(pv.x), w, a0); a1 = fmaf(bhi(pv.x), w, a1);
        a2 = fmaf(blo(pv.y), w, a2); a3 = fmaf(bhi(pv.y), w, a3);
        a4 = fmaf(blo(pv.z), w, a4); a5 = fmaf(bhi(pv.z), w, a5);
        a6 = fmaf(blo(pv.w), w, a6); a7 = fmaf(bhi(pv.w), w, a7);
    }
#define RED2(a) a += __shfl_xor(a, 16); a += __shfl_xor(a, 32);
    RED2(a0) RED2(a1) RED2(a2) RED2(a3) RED2(a4) RED2(a5) RED2(a6) RED2(a7)
#undef RED2

    if (g == 0) {
        const float r = 1.f / fmaxf(dg, 1.f);
        uint4 o;
        o.x = packbf(a0 * r, a1 * r);
        o.y = packbf(a2 * r, a3 * r);
        o.z = packbf(a4 * r, a5 * r);
        o.w = packbf(a6 * r, a7 * r);
        ((uint4*)((uint*)Pb + (size_t)v * 256 + 128))[gl] = o;
    }
}

// ---------------------------------------------------------------------------
// K5: gate_final (MFMA + fused finalize) — G = relu([h_in|h_out]@W_g1+b_g1)
//     stays in LDS; gate = sigmoid(G·W_g2+b_g2);
//     out = gate*h_in + (1-gate)*h_out + x.
// ---------------------------------------------------------------------------
__global__ __launch_bounds__(THREADS)
void gate_final(const ushort* __restrict__ Pb, const ushort* __restrict__ Hout,
                int M,
                const ushort* __restrict__ Wtg1, const float* __restrict__ b_g1,
                const float* __restrict__ W_g2, const float* __restrict__ b_g2,
                const float* __restrict__ x, float* __restrict__ out)
{
    __shared__ __align__(16) char AsB[16384];
    __shared__ __align__(16) char BtB[32768];

    const int tid = threadIdx.x;
    const int m0  = blockIdx.x * 64;
    const int wv = tid >> 6, ln = tid & 63;

    f32x4 acc[8];
#pragma unroll
    for (int tt = 0; tt < 8; ++tt) acc[tt] = (f32x4){0.f, 0.f, 0.f, 0.f};

    for (int h = 0; h < 2; ++h) {
        if (h) __syncthreads();
        // stage A half: h==0 -> h_in (Pb uint4 32..47), h==1 -> Hout row
        {
            const int r = tid >> 2, seg = tid & 3;
            int gr = m0 + r; if (gr >= M) gr = M - 1;
            const uint4* ps = (h == 0)
                ? ((const uint4*)Pb + (size_t)gr * 64 + 32 + seg * 4)
                : ((const uint4*)Hout + (size_t)gr * 16 + seg * 4);
#pragma unroll
            for (int i = 0; i < 4; ++i) {
                const uint4 u = ps[i];
                const int kbyte = seg * 64 + i * 16;
                *(uint4*)(AsB + r * 256 + (kbyte ^ ((r & 7) << 4))) = u;
            }
        }
        // stage Bt half from Wtg1 [128n][256k]
        {
            const int rn = tid >> 1, sg = tid & 1;
            const uint4* ws = (const uint4*)Wtg1 + (size_t)rn * 32 + h * 16 + sg * 8;
#pragma unroll
            for (int i = 0; i < 8; ++i) {
                const uint4 u = ws[i];
                const int kbyte = sg * 128 + i * 16;
                *(uint4*)(BtB + rn * 256 + (kbyte ^ ((rn & 7) << 4))) = u;
            }
        }
        __syncthreads();
        mfma_tile_compute(AsB, BtB, wv, ln, acc);
    }

    __syncthreads();                           // BtB reads done; reuse padded
    // G (relu'd) -> BtB padded rows (68 uints), packed uint writes
#pragma unroll
    for (int tt = 0; tt < 8; ++tt) {
        const int n = tt * 16 + (ln & 15);
        const float bv = b_g1[n];
#pragma unroll
        for (int r = 0; r < 4; ++r) {
            const int m = wv * 16 + ((ln >> 4) << 2) + r;
            const float val = fmaxf(acc[tt][r] + bv, 0.f);
            const float pr  = __shfl_xor(val, 1);
            if ((ln & 1) == 0)
                ((uint*)BtB)[m * 68 + (n >> 1)] = packbf(val, pr);
        }
    }
    __syncthreads();

    // fused finalize: wave wv handles rows wv*16 .. +15
    const float bg2 = b_g2[0];
    const float2 w2 = ((const float2*)W_g2)[ln];
#pragma unroll 4
    for (int r = 0; r < 16; ++r) {
        const int row = wv * 16 + r;
        const int gr  = m0 + row;
        const uint gv = ((const uint*)BtB)[row * 68 + ln];
        float part = blo(gv) * w2.x + bhi(gv) * w2.y;
#pragma unroll
        for (int off = 32; off; off >>= 1) part += __shfl_xor(part, off);
        const float gate = 1.f / (1.f + expf(-(part + bg2)));
        if (gr < M) {
            const uint hin = ((const uint*)Pb)[(size_t)gr * 256 + 128 + ln];
            const uint hov = ((const uint*)Hout)[(size_t)gr * 64 + ln];
            const float2 xv = ((const float2*)x)[(size_t)gr * 64 + ln];
            float2 o;
            o.x = gate * blo(hin) + (1.f - gate) * blo(hov) + xv.x;
            o.y = gate * bhi(hin) + (1.f - gate) * bhi(hov) + xv.y;
            ((float2*)out)[(size_t)gr * 64 + ln] = o;
        }
    }
}

// ---------------------------------------------------------------------------
extern "C" void kernel_launch(void* const* d_in, const int* in_sizes, int n_in,
                              void* d_out, int out_size, void* d_ws, size_t ws_size,
                              hipStream_t stream)
{
    const float* x     = (const float*)d_in[0];
    const int*   src   = (const int*)  d_in[1];
    const int*   dst   = (const int*)  d_in[2];
    const float* cnts  = (const float*)d_in[3];
    const float* W_sd  = (const float*)d_in[4];
    const float* b_sd  = (const float*)d_in[5];
    const float* W_ds  = (const float*)d_in[6];
    const float* b_ds  = (const float*)d_in[7];
    const float* W_l1  = (const float*)d_in[8];
    const float* b_l1  = (const float*)d_in[9];
    const float* W_l2  = (const float*)d_in[10];
    const float* b_l2  = (const float*)d_in[11];
    const float* W_g1  = (const float*)d_in[12];
    const float* b_g1  = (const float*)d_in[13];
    const float* W_g2  = (const float*)d_in[14];
    const float* b_g2  = (const float*)d_in[15];

    const int M = in_sizes[0] / 128;
    const int E = in_sizes[1];

    // workspace:
    //   Pb        : M*512 bf16   (p_sd | p_ds | a->h_in | bb)
    //   Wt        : 4*128*128 bf16
    //   Wtg1      : 128*256 bf16
    //   Hout      : M*128 bf16   (normalized h_out)
    //   packed_in : ull[M] (zeroed)   cnt<<32 | int(deg)
    //   cur_in    : int[M] (zeroed)
    //   uw_in     : float2[E]
    //   off_in    : int[M]
    //   off_out   : int[M+1]
    //   bsum      : int[(M+255)/256]
    ushort* Pb        = (ushort*)d_ws;
    ushort* Wt        = Pb + (size_t)M * 512;
    ushort* Wtg1      = Wt + 4 * 16384;
    ushort* Hout      = Wtg1 + 32768;
    ull*    packed_in = (ull*)(Hout + (size_t)M * 128);
    int*    cur_in    = (int*)(packed_in + M);
    float2* uw_in     = (float2*)(cur_in + M);
    int*    off_in    = (int*)(uw_in + E);
    int*    off_out   = off_in + M;
    int*    bsum      = off_out + M + 1;

    // zero packed_in + cur_in (contiguous 12*M bytes)
    hipMemsetAsync(packed_in, 0, 12 * (size_t)M, stream);

    transpose_w<<<dim3(16, 6), THREADS, 0, stream>>>(W_sd, W_ds, W_l1, W_g1, Wt, Wtg1);

    const int gx = (M + 63) / 64;
    gemm_node_count<<<NC + gx, THREADS, 0, stream>>>(
        x, M, Wt, b_sd, b_ds, b_l1, Pb, src, dst, cnts, packed_in, off_out, E);

    const int NB = (M + 255) / 256;     // 196 for M=50000 (must be <= 1024)
    scan_p1<<<NB, 256, 0, stream>>>(packed_in, bsum, M);
    scan_p2<<<1, 1024, 0, stream>>>(bsum, NB);
    scan_p3<<<NB, 256, 0, stream>>>(packed_in, bsum, off_in, M);

    edge_out<<<(M + 3) / 4, THREADS, 0, stream>>>(
        Pb, Hout, dst, cnts, W_l2, b_l2, off_out, off_in, cur_in, uw_in, M);

    agg_in<<<(M + 3) / 4, THREADS, 0, stream>>>(Pb, uw_in, off_in, packed_in, M);

    gate_final<<<gx, THREADS, 0, stream>>>(Pb, Hout, M, Wtg1, b_g1, W_g2, b_g2,
                                           x, (float*)d_out);
}

// Round 11
// 186.511 us; speedup vs baseline: 1.0732x; 1.0732x over previous
//
#include <hip/hip_runtime.h>
#include <math.h>

typedef unsigned int uint;
typedef unsigned long long ull;

#define THREADS 256
#define NC 96          // counting blocks at head of fused grid

typedef __attribute__((ext_vector_type(8))) short bf16x8;
typedef __attribute__((ext_vector_type(4))) float f32x4;

// ---- bf16 helpers (storage-only; math in fp32 / MFMA-fp32-accum) ----------
__device__ __forceinline__ float blo(uint u) { return __uint_as_float(u << 16); }
__device__ __forceinline__ float bhi(uint u) { return __uint_as_float(u & 0xffff0000u); }
__device__ __forceinline__ uint  bf16r(float x) {           // RTNE
    uint u = __float_as_uint(x);
    return (u + 0x7fffu + ((u >> 16) & 1u)) >> 16;
}
__device__ __forceinline__ uint packbf(float lo, float hi) {
    return bf16r(lo) | (bf16r(hi) << 16);
}

// ---------------------------------------------------------------------------
// K0: transpose weights to bf16 Wt[n][k] once.
// ---------------------------------------------------------------------------
__global__ __launch_bounds__(THREADS)
void transpose_w(const float* __restrict__ W_sd, const float* __restrict__ W_ds,
                 const float* __restrict__ W_l1, const float* __restrict__ W_g1,
                 ushort* __restrict__ Wt, ushort* __restrict__ Wtg1)
{
    __shared__ float tile[32][33];
    const int y = blockIdx.y;
    const float* src;
    ushort* dst;
    int dstK, kofs;
    if (y < 4) {
        src = (y == 0) ? W_sd : (y == 1) ? W_ds : (y == 2) ? W_l1 : (W_l1 + 16384);
        dst = Wt + y * 16384; dstK = 128; kofs = 0;
    } else {
        src = W_g1 + (y - 4) * 16384;
        dst = Wtg1; dstK = 256; kofs = (y - 4) * 128;
    }
    const int tix = blockIdx.x;
    const int k0 = (tix & 3) * 32, n0 = (tix >> 2) * 32;
    const int t = threadIdx.x;

    {
        const int r = t >> 3, c8 = t & 7;
        const float4 f = *(const float4*)(src + (size_t)(k0 + r) * 128 + n0 + c8 * 4);
        tile[r][c8 * 4 + 0] = f.x; tile[r][c8 * 4 + 1] = f.y;
        tile[r][c8 * 4 + 2] = f.z; tile[r][c8 * 4 + 3] = f.w;
    }
    __syncthreads();
    {
        const int n = t >> 3, k8 = t & 7;
        const float v0 = tile[k8 * 4 + 0][n], v1 = tile[k8 * 4 + 1][n];
        const float v2 = tile[k8 * 4 + 2][n], v3 = tile[k8 * 4 + 3][n];
        uint2 o; o.x = packbf(v0, v1); o.y = packbf(v2, v3);
        *(uint2*)(dst + (size_t)(n0 + n) * dstK + kofs + k0 + k8 * 4) = o;
    }
}

// ---------------------------------------------------------------------------
// shared MFMA tile body: As 64x128 bf16 (16KB), Bt 128x128 bf16 (32KB),
// XOR-swizzle kbyte ^= (row&7)<<4 on both; 4 waves x 16 rows x 128 cols.
// ---------------------------------------------------------------------------
__device__ __forceinline__ void mfma_tile_compute(const char* AsB, const char* BtB,
                                                  int wv, int ln, f32x4 acc[8])
{
    const int mrow = wv * 16 + (ln & 15);
    const int kgb  = (ln >> 4) * 16;                 // k-group byte offset
#pragma unroll
    for (int kk = 0; kk < 4; ++kk) {
        const int kbyte = kk * 64 + kgb;
        const bf16x8 a = *(const bf16x8*)(AsB + mrow * 256 + (kbyte ^ ((mrow & 7) << 4)));
#pragma unroll
        for (int tt = 0; tt < 8; ++tt) {
            const int nrow = tt * 16 + (ln & 15);
            const bf16x8 b = *(const bf16x8*)(BtB + nrow * 256 + (kbyte ^ ((nrow & 7) << 4)));
            acc[tt] = __builtin_amdgcn_mfma_f32_16x16x32_bf16(a, b, acc[tt], 0, 0, 0);
        }
    }
}

// ---------------------------------------------------------------------------
// K1 (fused, 1D grid = NC + 4*BPG):
//   bid < NC  -> edge counting (1 packed atomic/edge on dst) + off_out fill
//                from SORTED src (np.unique lex order). Grid-stride.
//   bid >= NC -> WEIGHT-STATIONARY GEMM: q = bid-NC, grp = q&3, sidx = q>>2.
//                Stage Bt(grp) ONCE; loop 4 consecutive 64-row strips
//                (sidx*4+k): A prefetched to regs during prior strip's MFMA.
//                Groups sharing a strip are dispatch-adjacent -> X L2 reuse.
// ---------------------------------------------------------------------------
__global__ __launch_bounds__(THREADS)
void gemm_node_count(const float* __restrict__ X, int M,
                     const ushort* __restrict__ Wt,
                     const float* __restrict__ b_sd, const float* __restrict__ b_ds,
                     const float* __restrict__ b_l1,
                     ushort* __restrict__ Pb,
                     const int* __restrict__ src, const int* __restrict__ dst,
                     const float* __restrict__ counts,
                     ull* __restrict__ packed_in, int* __restrict__ off_out,
                     int E, int ST, int BPG)
{
    __shared__ __align__(16) char BtB[32768];
    __shared__ __align__(16) char AsB[17408];   // A: 64x256B ; epilogue: 64x272B

    const int tid = threadIdx.x;
    const int bid = blockIdx.x;

    if (bid < NC) {
        const int stride = NC * THREADS;
        for (int e = bid * THREADS + tid; e < E; e += stride) {
            const int  d = dst[e];
            const uint c = (uint)counts[e];
            atomicAdd(packed_in + d, (1ULL << 32) | (ull)c);
        }
        // off_out: first edge index with src >= v (src sorted non-decreasing)
        for (int e = bid * THREADS + tid; e < E; e += stride) {
            const int cur  = src[e];
            const int prev = (e == 0) ? -1 : src[e - 1];
            for (int v = prev + 1; v <= cur; ++v) off_out[v] = e;
            if (e == E - 1)
                for (int v = cur + 1; v <= M; ++v) off_out[v] = E;
        }
        return;
    }

    const int q    = bid - NC;
    const int grp  = q & 3;
    const int sidx = q >> 2;
    const int wv = tid >> 6, ln = tid & 63;
    const int r = tid >> 2, seg = tid & 3;      // A-staging / store role

    if (sidx * 4 >= ST) return;                 // uniform

    // ---- stage Bt(grp) ONCE (128 n-rows x 128 k, bf16 from L2, swizzled) --
    {
        const int rn = tid >> 1, sg = tid & 1;
        const uint4* ws = (const uint4*)(Wt + grp * 16384 + (size_t)rn * 128 + sg * 64);
#pragma unroll
        for (int i = 0; i < 8; ++i) {
            const uint4 u = ws[i];
            const int kbyte = sg * 128 + i * 16;
            *(uint4*)(BtB + rn * 256 + (kbyte ^ ((rn & 7) << 4))) = u;
        }
    }

    const float* bias = (grp == 0) ? b_sd : (grp == 1) ? b_ds
                      : (grp == 2) ? b_l1 : nullptr;
    float bv[8];
#pragma unroll
    for (int tt = 0; tt < 8; ++tt)
        bv[tt] = bias ? bias[tt * 16 + (ln & 15)] : 0.f;

    // ---- prefetch strip 0 into regs ----
    float4 fa[8];
    {
        int gr = sidx * 4 * 64 + r; if (gr >= M) gr = M - 1;
        const float4* xs = (const float4*)(X + (size_t)gr * 128 + seg * 32);
#pragma unroll
        for (int i = 0; i < 8; ++i) fa[i] = xs[i];
    }

    for (int k = 0; k < 4; ++k) {
        const int s = sidx * 4 + k;
        if (s >= ST) break;
        __syncthreads();                 // AsB free; Bt visible (k==0)

        // write A regs -> AsB (256B-stride rows, swizzled, fp32->bf16)
#pragma unroll
        for (int i = 0; i < 4; ++i) {
            const float4 f0 = fa[i * 2], f1 = fa[i * 2 + 1];
            uint4 u;
            u.x = packbf(f0.x, f0.y); u.y = packbf(f0.z, f0.w);
            u.z = packbf(f1.x, f1.y); u.w = packbf(f1.z, f1.w);
            const int kbyte = seg * 64 + i * 16;
            *(uint4*)(AsB + r * 256 + (kbyte ^ ((r & 7) << 4))) = u;
        }
        __syncthreads();                 // A visible

        // prefetch next strip while MFMAs run
        if (k < 3 && s + 1 < ST) {
            int gr = (s + 1) * 64 + r; if (gr >= M) gr = M - 1;
            const float4* xs = (const float4*)(X + (size_t)gr * 128 + seg * 32);
#pragma unroll
            for (int i = 0; i < 8; ++i) fa[i] = xs[i];
        }

        f32x4 acc[8];
#pragma unroll
        for (int tt = 0; tt < 8; ++tt) acc[tt] = (f32x4){0.f, 0.f, 0.f, 0.f};
        mfma_tile_compute(AsB, BtB, wv, ln, acc);
        __syncthreads();                 // AsB reads done

        // epilogue: bias+bf16 -> AsB padded rows (136 ushort = 272B stride)
#pragma unroll
        for (int tt = 0; tt < 8; ++tt) {
            const int n = tt * 16 + (ln & 15);
#pragma unroll
            for (int r2 = 0; r2 < 4; ++r2) {
                const int m = wv * 16 + ((ln >> 4) << 2) + r2;
                ((ushort*)AsB)[m * 136 + n] = (ushort)bf16r(acc[tt][r2] + bv[tt]);
            }
        }
        __syncthreads();

        // coalesced store AsB -> Pb
        {
            const int gr = s * 64 + r;
            if (gr < M) {
                uint4* dstp = (uint4*)Pb + (size_t)gr * 64 + grp * 16 + seg * 4;
#pragma unroll
                for (int i = 0; i < 4; ++i)
                    dstp[i] = *(const uint4*)(AsB + r * 272 + (seg * 4 + i) * 16);
            }
        }
    }
}

// ---------------------------------------------------------------------------
// K2a/b/c: hierarchical exclusive scan of hi32(packed_in) -> off_in.
// ---------------------------------------------------------------------------
__global__ __launch_bounds__(256)
void scan_p1(const ull* __restrict__ packed_in, int* __restrict__ bsum, int M)
{
    __shared__ int s[256];
    const int t = threadIdx.x;
    const int i = blockIdx.x * 256 + t;
    s[t] = (i < M) ? (int)(packed_in[i] >> 32) : 0;
    __syncthreads();
#pragma unroll
    for (int o = 128; o; o >>= 1) {
        if (t < o) s[t] += s[t + o];
        __syncthreads();
    }
    if (t == 0) bsum[blockIdx.x] = s[0];
}

__global__ __launch_bounds__(1024)
void scan_p2(int* __restrict__ bsum, int NB)
{
    __shared__ int s[1024];
    const int t = threadIdx.x;
    const int v = (t < NB) ? bsum[t] : 0;
    s[t] = v;
    __syncthreads();
    for (int o = 1; o < 1024; o <<= 1) {
        const int u = (t >= o) ? s[t - o] : 0;
        __syncthreads();
        s[t] += u;
        __syncthreads();
    }
    if (t < NB) bsum[t] = s[t] - v;   // exclusive
}

__global__ __launch_bounds__(256)
void scan_p3(const ull* __restrict__ packed_in, const int* __restrict__ bsum,
             int* __restrict__ off_in, int M)
{
    __shared__ int s[256];
    const int t = threadIdx.x;
    const int i = blockIdx.x * 256 + t;
    const int v = (i < M) ? (int)(packed_in[i] >> 32) : 0;
    s[t] = v;
    __syncthreads();
    for (int o = 1; o < 256; o <<= 1) {
        const int u = (t >= o) ? s[t - o] : 0;
        __syncthreads();
        s[t] += u;
        __syncthreads();
    }
    if (i < M) off_in[i] = bsum[blockIdx.x] + s[t] - v;
}

// ---------------------------------------------------------------------------
// K3: edge_out — 1 wave per src node (sorted-src run). a[v] in registers;
//     per edge: gather bb[d] + p_ds[d], lcs in 16-lane groups (4 edges in
//     flight), fill in-CSR slot (u=v, w), accumulate h_out -> Hout[v].
// ---------------------------------------------------------------------------
__global__ __launch_bounds__(THREADS)
void edge_out(const ushort* __restrict__ Pb, ushort* __restrict__ Hout,
              const int* __restrict__ dst, const float* __restrict__ counts,
              const float* __restrict__ W_l2, const float* __restrict__ b_l2,
              const int* __restrict__ off_out,
              const int* __restrict__ off_in, int* __restrict__ cur_in,
              float2* __restrict__ uw_in, int M)
{
    const int lane = threadIdx.x & 63;
    const int wid  = threadIdx.x >> 6;
    const int v    = blockIdx.x * 4 + wid;
    if (v >= M) return;
    const int g  = lane >> 4;       // edge group 0..3
    const int gl = lane & 15;       // 8 elems per lane

    const uint* rs = (const uint*)Pb + (size_t)v * 256;
    const uint4 av = ((const uint4*)(rs + 128))[gl];       // a[v], elems 256..383
    const float4 wa = ((const float4*)W_l2)[gl * 2];
    const float4 wb = ((const float4*)W_l2)[gl * 2 + 1];
    const float bl2 = b_l2[0];

    const int base = off_out[v];
    const int end  = off_out[v + 1];

    float a0 = 0.f, a1 = 0.f, a2 = 0.f, a3 = 0.f;
    float a4 = 0.f, a5 = 0.f, a6 = 0.f, a7 = 0.f;
    float dg = 0.f;

    for (int j = base + g; j < end; j += 4) {
        const int   d = dst[j];
        const float c = counts[j];
        const uint* rd = (const uint*)Pb + (size_t)d * 256;
        const uint4 bv = ((const uint4*)(rd + 192))[gl];   // bb[d], elems 384..511
        const uint4 pv = ((const uint4*)(rd + 64))[gl];    // p_ds[d], elems 128..255

        float part =
            fmaxf(blo(av.x) + blo(bv.x), 0.f) * wa.x + fmaxf(bhi(av.x) + bhi(bv.x), 0.f) * wa.y +
            fmaxf(blo(av.y) + blo(bv.y), 0.f) * wa.z + fmaxf(bhi(av.y) + bhi(bv.y), 0.f) * wa.w +
            fmaxf(blo(av.z) + blo(bv.z), 0.f) * wb.x + fmaxf(bhi(av.z) + bhi(bv.z), 0.f) * wb.y +
            fmaxf(blo(av.w) + blo(bv.w), 0.f) * wb.z + fmaxf(bhi(av.w) + bhi(bv.w), 0.f) * wb.w;
        part += __shfl_xor(part, 1);
        part += __shfl_xor(part, 2);
        part += __shfl_xor(part, 4);
        part += __shfl_xor(part, 8);

        const float w = (1.f / (1.f + expf(-(part + bl2)))) * c;

        a0 = fmaf(blo(pv.x), w, a0); a1 = fmaf(bhi(pv.x), w, a1);
        a2 = fmaf(blo(pv.y), w, a2); a3 = fmaf(bhi(pv.y), w, a3);
        a4 = fmaf(blo(pv.z), w, a4); a5 = fmaf(bhi(pv.z), w, a5);
        a6 = fmaf(blo(pv.w), w, a6); a7 = fmaf(bhi(pv.w), w, a7);
        dg += c;

        if (gl == 0) {
            const int r1 = atomicAdd(cur_in + d, 1);
            uw_in[off_in[d] + r1] = make_float2(__int_as_float(v), w);
        }
    }

#define RED2(a) a += __shfl_xor(a, 16); a += __shfl_xor(a, 32);
    RED2(a0) RED2(a1) RED2(a2) RED2(a3) RED2(a4) RED2(a5) RED2(a6) RED2(a7) RED2(dg)
#undef RED2

    if (g == 0) {
        const float r = 1.f / fmaxf(dg, 1.f);
        uint4 o;
        o.x = packbf(a0 * r, a1 * r);
        o.y = packbf(a2 * r, a3 * r);
        o.z = packbf(a4 * r, a5 * r);
        o.w = packbf(a6 * r, a7 * r);
        ((uint4*)((uint*)Hout + (size_t)v * 64))[gl] = o;
    }
}

// ---------------------------------------------------------------------------
// K4: agg_in — 1 wave per node: walk uw_in CSR, gather p_sd rows, normalize
//     by deg (lo32 of packed). Writes h_in -> Pb elems 256..383 (a is dead).
// ---------------------------------------------------------------------------
__global__ __launch_bounds__(THREADS)
void agg_in(ushort* __restrict__ Pb,
            const float2* __restrict__ uw_in,
            const int* __restrict__ off_in, const ull* __restrict__ packed_in,
            int M)
{
    const int lane = threadIdx.x & 63;
    const int wid  = threadIdx.x >> 6;
    const int v    = blockIdx.x * 4 + wid;
    if (v >= M) return;
    const int g  = lane >> 4;
    const int gl = lane & 15;

    const ull pk = packed_in[v];
    const int n  = (int)(pk >> 32);
    const float dg = (float)(uint)(pk & 0xffffffffu);
    const float2* __restrict__ uw = uw_in + off_in[v];

    float a0 = 0.f, a1 = 0.f, a2 = 0.f, a3 = 0.f;
    float a4 = 0.f, a5 = 0.f, a6 = 0.f, a7 = 0.f;
    for (int j = g; j < n; j += 4) {
        const float2 p = uw[j];
        const int    u = __float_as_int(p.x);
        const float  w = p.y;
        const uint4 pv = ((const uint4*)((const uint*)Pb + (size_t)u * 256))[gl];
        a0 = fmaf(blo(pv.x), w, a0); a1 = fmaf(bhi(pv.x), w, a1);
        a2 = fmaf(blo(pv.y), w, a2); a3 = fmaf(bhi(pv.y), w, a3);
        a4 = fmaf(blo(pv.z), w, a4); a5 = fmaf(bhi(pv.z), w, a5);
        a6 = fmaf(blo(pv.w), w, a6); a7 = fmaf(bhi(pv.w), w, a7);
    }
#define RED2(a) a += __shfl_xor(a, 16); a += __shfl_xor(a, 32);
    RED2(a0) RED2(a1) RED2(a2) RED2(a3) RED2(a4) RED2(a5) RED2(a6) RED2(a7)
#undef RED2

    if (g == 0) {
        const float r = 1.f / fmaxf(dg, 1.f);
        uint4 o;
        o.x = packbf(a0 * r, a1 * r);
        o.y = packbf(a2 * r, a3 * r);
        o.z = packbf(a4 * r, a5 * r);
        o.w = packbf(a6 * r, a7 * r);
        ((uint4*)((uint*)Pb + (size_t)v * 256 + 128))[gl] = o;
    }
}

// ---------------------------------------------------------------------------
// K5: gate_final (MFMA + fused finalize) — G = relu([h_in|h_out]@W_g1+b_g1)
//     stays in LDS; gate = sigmoid(G·W_g2+b_g2);
//     out = gate*h_in + (1-gate)*h_out + x.
// ---------------------------------------------------------------------------
__global__ __launch_bounds__(THREADS)
void gate_final(const ushort* __restrict__ Pb, const ushort* __restrict__ Hout,
                int M,
                const ushort* __restrict__ Wtg1, const float* __restrict__ b_g1,
                const float* __restrict__ W_g2, const float* __restrict__ b_g2,
                const float* __restrict__ x, float* __restrict__ out)
{
    __shared__ __align__(16) char AsB[16384];
    __shared__ __align__(16) char BtB[32768];

    const int tid = threadIdx.x;
    const int m0  = blockIdx.x * 64;
    const int wv = tid >> 6, ln = tid & 63;

    f32x4 acc[8];
#pragma unroll
    for (int tt = 0; tt < 8; ++tt) acc[tt] = (f32x4){0.f, 0.f, 0.f, 0.f};

    for (int h = 0; h < 2; ++h) {
        if (h) __syncthreads();
        // stage A half: h==0 -> h_in (Pb uint4 32..47), h==1 -> Hout row
        {
            const int r = tid >> 2, seg = tid & 3;
            int gr = m0 + r; if (gr >= M) gr = M - 1;
            const uint4* ps = (h == 0)
                ? ((const uint4*)Pb + (size_t)gr * 64 + 32 + seg * 4)
                : ((const uint4*)Hout + (size_t)gr * 16 + seg * 4);
#pragma unroll
            for (int i = 0; i < 4; ++i) {
                const uint4 u = ps[i];
                const int kbyte = seg * 64 + i * 16;
                *(uint4*)(AsB + r * 256 + (kbyte ^ ((r & 7) << 4))) = u;
            }
        }
        // stage Bt half from Wtg1 [128n][256k]
        {
            const int rn = tid >> 1, sg = tid & 1;
            const uint4* ws = (const uint4*)Wtg1 + (size_t)rn * 32 + h * 16 + sg * 8;
#pragma unroll
            for (int i = 0; i < 8; ++i) {
                const uint4 u = ws[i];
                const int kbyte = sg * 128 + i * 16;
                *(uint4*)(BtB + rn * 256 + (kbyte ^ ((rn & 7) << 4))) = u;
            }
        }
        __syncthreads();
        mfma_tile_compute(AsB, BtB, wv, ln, acc);
    }

    __syncthreads();                           // BtB reads done; reuse padded
    // G (relu'd) -> BtB padded rows (68 uints), packed uint writes
#pragma unroll
    for (int tt = 0; tt < 8; ++tt) {
        const int n = tt * 16 + (ln & 15);
        const float bv = b_g1[n];
#pragma unroll
        for (int r = 0; r < 4; ++r) {
            const int m = wv * 16 + ((ln >> 4) << 2) + r;
            const float val = fmaxf(acc[tt][r] + bv, 0.f);
            const float pr  = __shfl_xor(val, 1);
            if ((ln & 1) == 0)
                ((uint*)BtB)[m * 68 + (n >> 1)] = packbf(val, pr);
        }
    }
    __syncthreads();

    // fused finalize: wave wv handles rows wv*16 .. +15
    const float bg2 = b_g2[0];
    const float2 w2 = ((const float2*)W_g2)[ln];
#pragma unroll 4
    for (int r = 0; r < 16; ++r) {
        const int row = wv * 16 + r;
        const int gr  = m0 + row;
        const uint gv = ((const uint*)BtB)[row * 68 + ln];
        float part = blo(gv) * w2.x + bhi(gv) * w2.y;
#pragma unroll
        for (int off = 32; off; off >>= 1) part += __shfl_xor(part, off);
        const float gate = 1.f / (1.f + expf(-(part + bg2)));
        if (gr < M) {
            const uint hin = ((const uint*)Pb)[(size_t)gr * 256 + 128 + ln];
            const uint hov = ((const uint*)Hout)[(size_t)gr * 64 + ln];
            const float2 xv = ((const float2*)x)[(size_t)gr * 64 + ln];
            float2 o;
            o.x = gate * blo(hin) + (1.f - gate) * blo(hov) + xv.x;
            o.y = gate * bhi(hin) + (1.f - gate) * bhi(hov) + xv.y;
            ((float2*)out)[(size_t)gr * 64 + ln] = o;
        }
    }
}

// ---------------------------------------------------------------------------
extern "C" void kernel_launch(void* const* d_in, const int* in_sizes, int n_in,
                              void* d_out, int out_size, void* d_ws, size_t ws_size,
                              hipStream_t stream)
{
    const float* x     = (const float*)d_in[0];
    const int*   src   = (const int*)  d_in[1];
    const int*   dst   = (const int*)  d_in[2];
    const float* cnts  = (const float*)d_in[3];
    const float* W_sd  = (const float*)d_in[4];
    const float* b_sd  = (const float*)d_in[5];
    const float* W_ds  = (const float*)d_in[6];
    const float* b_ds  = (const float*)d_in[7];
    const float* W_l1  = (const float*)d_in[8];
    const float* b_l1  = (const float*)d_in[9];
    const float* W_l2  = (const float*)d_in[10];
    const float* b_l2  = (const float*)d_in[11];
    const float* W_g1  = (const float*)d_in[12];
    const float* b_g1  = (const float*)d_in[13];
    const float* W_g2  = (const float*)d_in[14];
    const float* b_g2  = (const float*)d_in[15];

    const int M = in_sizes[0] / 128;
    const int E = in_sizes[1];

    // workspace:
    //   Pb        : M*512 bf16   (p_sd | p_ds | a->h_in | bb)
    //   Wt        : 4*128*128 bf16
    //   Wtg1      : 128*256 bf16
    //   Hout      : M*128 bf16   (normalized h_out)
    //   packed_in : ull[M] (zeroed)   cnt<<32 | int(deg)
    //   cur_in    : int[M] (zeroed)
    //   uw_in     : float2[E]
    //   off_in    : int[M]
    //   off_out   : int[M+1]
    //   bsum      : int[(M+255)/256]
    ushort* Pb        = (ushort*)d_ws;
    ushort* Wt        = Pb + (size_t)M * 512;
    ushort* Wtg1      = Wt + 4 * 16384;
    ushort* Hout      = Wtg1 + 32768;
    ull*    packed_in = (ull*)(Hout + (size_t)M * 128);
    int*    cur_in    = (int*)(packed_in + M);
    float2* uw_in     = (float2*)(cur_in + M);
    int*    off_in    = (int*)(uw_in + E);
    int*    off_out   = off_in + M;
    int*    bsum      = off_out + M + 1;

    // zero packed_in + cur_in (contiguous 12*M bytes)
    hipMemsetAsync(packed_in, 0, 12 * (size_t)M, stream);

    transpose_w<<<dim3(16, 6), THREADS, 0, stream>>>(W_sd, W_ds, W_l1, W_g1, Wt, Wtg1);

    const int ST  = (M + 63) / 64;      // 782 strips
    const int BPG = (ST + 3) / 4;       // 196 strip-sets per group
    gemm_node_count<<<NC + 4 * BPG, THREADS, 0, stream>>>(
        x, M, Wt, b_sd, b_ds, b_l1, Pb, src, dst, cnts, packed_in, off_out,
        E, ST, BPG);

    const int NB = (M + 255) / 256;     // 196 (must be <= 1024)
    scan_p1<<<NB, 256, 0, stream>>>(packed_in, bsum, M);
    scan_p2<<<1, 1024, 0, stream>>>(bsum, NB);
    scan_p3<<<NB, 256, 0, stream>>>(packed_in, bsum, off_in, M);

    edge_out<<<(M + 3) / 4, THREADS, 0, stream>>>(
        Pb, Hout, dst, cnts, W_l2, b_l2, off_out, off_in, cur_in, uw_in, M);

    agg_in<<<(M + 3) / 4, THREADS, 0, stream>>>(Pb, uw_in, off_in, packed_in, M);

    gate_final<<<(M + 63) / 64, THREADS, 0, stream>>>(Pb, Hout, M, Wtg1, b_g1,
                                                      W_g2, b_g2, x, (float*)d_out);
}

// Round 12
// 182.207 us; speedup vs baseline: 1.0985x; 1.0236x over previous
//
#include <hip/hip_runtime.h>
#include <math.h>

typedef unsigned int uint;
typedef unsigned long long ull;

#define THREADS 256
#define NC 96          // counting blocks at head of fused grid

typedef __attribute__((ext_vector_type(8))) short bf16x8;
typedef __attribute__((ext_vector_type(4))) float f32x4;

// ---- bf16 helpers (storage-only; math in fp32 / MFMA-fp32-accum) ----------
__device__ __forceinline__ float blo(uint u) { return __uint_as_float(u << 16); }
__device__ __forceinline__ float bhi(uint u) { return __uint_as_float(u & 0xffff0000u); }
__device__ __forceinline__ uint  bf16r(float x) {           // RTNE
    uint u = __float_as_uint(x);
    return (u + 0x7fffu + ((u >> 16) & 1u)) >> 16;
}
__device__ __forceinline__ uint packbf(float lo, float hi) {
    return bf16r(lo) | (bf16r(hi) << 16);
}

// ---------------------------------------------------------------------------
// K0: transpose weights to bf16 Wt[n][k] once.
// ---------------------------------------------------------------------------
__global__ __launch_bounds__(THREADS)
void transpose_w(const float* __restrict__ W_sd, const float* __restrict__ W_ds,
                 const float* __restrict__ W_l1, const float* __restrict__ W_g1,
                 ushort* __restrict__ Wt, ushort* __restrict__ Wtg1)
{
    __shared__ float tile[32][33];
    const int y = blockIdx.y;
    const float* src;
    ushort* dst;
    int dstK, kofs;
    if (y < 4) {
        src = (y == 0) ? W_sd : (y == 1) ? W_ds : (y == 2) ? W_l1 : (W_l1 + 16384);
        dst = Wt + y * 16384; dstK = 128; kofs = 0;
    } else {
        src = W_g1 + (y - 4) * 16384;
        dst = Wtg1; dstK = 256; kofs = (y - 4) * 128;
    }
    const int tix = blockIdx.x;
    const int k0 = (tix & 3) * 32, n0 = (tix >> 2) * 32;
    const int t = threadIdx.x;

    {
        const int r = t >> 3, c8 = t & 7;
        const float4 f = *(const float4*)(src + (size_t)(k0 + r) * 128 + n0 + c8 * 4);
        tile[r][c8 * 4 + 0] = f.x; tile[r][c8 * 4 + 1] = f.y;
        tile[r][c8 * 4 + 2] = f.z; tile[r][c8 * 4 + 3] = f.w;
    }
    __syncthreads();
    {
        const int n = t >> 3, k8 = t & 7;
        const float v0 = tile[k8 * 4 + 0][n], v1 = tile[k8 * 4 + 1][n];
        const float v2 = tile[k8 * 4 + 2][n], v3 = tile[k8 * 4 + 3][n];
        uint2 o; o.x = packbf(v0, v1); o.y = packbf(v2, v3);
        *(uint2*)(dst + (size_t)(n0 + n) * dstK + kofs + k0 + k8 * 4) = o;
    }
}

// ---------------------------------------------------------------------------
// shared MFMA tile body: As 64x128 bf16 (16KB), Bt 128x128 bf16 (32KB),
// XOR-swizzle kbyte ^= (row&7)<<4 on both; 4 waves x 16 rows x 128 cols.
// ---------------------------------------------------------------------------
__device__ __forceinline__ void mfma_tile_compute(const char* AsB, const char* BtB,
                                                  int wv, int ln, f32x4 acc[8])
{
    const int mrow = wv * 16 + (ln & 15);
    const int kgb  = (ln >> 4) * 16;                 // k-group byte offset
#pragma unroll
    for (int kk = 0; kk < 4; ++kk) {
        const int kbyte = kk * 64 + kgb;
        const bf16x8 a = *(const bf16x8*)(AsB + mrow * 256 + (kbyte ^ ((mrow & 7) << 4)));
#pragma unroll
        for (int tt = 0; tt < 8; ++tt) {
            const int nrow = tt * 16 + (ln & 15);
            const bf16x8 b = *(const bf16x8*)(BtB + nrow * 256 + (kbyte ^ ((nrow & 7) << 4)));
            acc[tt] = __builtin_amdgcn_mfma_f32_16x16x32_bf16(a, b, acc[tt], 0, 0, 0);
        }
    }
}

// ---------------------------------------------------------------------------
// K1 (fused, 1D grid = NC + 4*BPG):
//   bid < NC  -> edge counting (1 packed atomic/edge on dst) + off_out fill
//                from SORTED src (np.unique lex order). Grid-stride.
//   bid >= NC -> WEIGHT-STATIONARY GEMM: q = bid-NC, grp = q&3, sidx = q>>2.
//                Stage Bt(grp) ONCE; loop 4 consecutive 64-row strips
//                (sidx*4+k): A prefetched to regs during prior strip's MFMA.
// ---------------------------------------------------------------------------
__global__ __launch_bounds__(THREADS)
void gemm_node_count(const float* __restrict__ X, int M,
                     const ushort* __restrict__ Wt,
                     const float* __restrict__ b_sd, const float* __restrict__ b_ds,
                     const float* __restrict__ b_l1,
                     ushort* __restrict__ Pb,
                     const int* __restrict__ src, const int* __restrict__ dst,
                     const float* __restrict__ counts,
                     ull* __restrict__ packed_in, int* __restrict__ off_out,
                     int E, int ST, int BPG)
{
    __shared__ __align__(16) char BtB[32768];
    __shared__ __align__(16) char AsB[17408];   // A: 64x256B ; epilogue: 64x272B

    const int tid = threadIdx.x;
    const int bid = blockIdx.x;

    if (bid < NC) {
        const int stride = NC * THREADS;
        for (int e = bid * THREADS + tid; e < E; e += stride) {
            const int  d = dst[e];
            const uint c = (uint)counts[e];
            atomicAdd(packed_in + d, (1ULL << 32) | (ull)c);
        }
        // off_out: first edge index with src >= v (src sorted non-decreasing)
        for (int e = bid * THREADS + tid; e < E; e += stride) {
            const int cur  = src[e];
            const int prev = (e == 0) ? -1 : src[e - 1];
            for (int v = prev + 1; v <= cur; ++v) off_out[v] = e;
            if (e == E - 1)
                for (int v = cur + 1; v <= M; ++v) off_out[v] = E;
        }
        return;
    }

    const int q    = bid - NC;
    const int grp  = q & 3;
    const int sidx = q >> 2;
    const int wv = tid >> 6, ln = tid & 63;
    const int r = tid >> 2, seg = tid & 3;      // A-staging / store role

    if (sidx * 4 >= ST) return;                 // uniform

    // ---- stage Bt(grp) ONCE (128 n-rows x 128 k, bf16 from L2, swizzled) --
    {
        const int rn = tid >> 1, sg = tid & 1;
        const uint4* ws = (const uint4*)(Wt + grp * 16384 + (size_t)rn * 128 + sg * 64);
#pragma unroll
        for (int i = 0; i < 8; ++i) {
            const uint4 u = ws[i];
            const int kbyte = sg * 128 + i * 16;
            *(uint4*)(BtB + rn * 256 + (kbyte ^ ((rn & 7) << 4))) = u;
        }
    }

    const float* bias = (grp == 0) ? b_sd : (grp == 1) ? b_ds
                      : (grp == 2) ? b_l1 : nullptr;
    float bv[8];
#pragma unroll
    for (int tt = 0; tt < 8; ++tt)
        bv[tt] = bias ? bias[tt * 16 + (ln & 15)] : 0.f;

    // ---- prefetch strip 0 into regs ----
    float4 fa[8];
    {
        int gr = sidx * 4 * 64 + r; if (gr >= M) gr = M - 1;
        const float4* xs = (const float4*)(X + (size_t)gr * 128 + seg * 32);
#pragma unroll
        for (int i = 0; i < 8; ++i) fa[i] = xs[i];
    }

    for (int k = 0; k < 4; ++k) {
        const int s = sidx * 4 + k;
        if (s >= ST) break;
        __syncthreads();                 // AsB free; Bt visible (k==0)

        // write A regs -> AsB (256B-stride rows, swizzled, fp32->bf16)
#pragma unroll
        for (int i = 0; i < 4; ++i) {
            const float4 f0 = fa[i * 2], f1 = fa[i * 2 + 1];
            uint4 u;
            u.x = packbf(f0.x, f0.y); u.y = packbf(f0.z, f0.w);
            u.z = packbf(f1.x, f1.y); u.w = packbf(f1.z, f1.w);
            const int kbyte = seg * 64 + i * 16;
            *(uint4*)(AsB + r * 256 + (kbyte ^ ((r & 7) << 4))) = u;
        }
        __syncthreads();                 // A visible

        // prefetch next strip while MFMAs run
        if (k < 3 && s + 1 < ST) {
            int gr = (s + 1) * 64 + r; if (gr >= M) gr = M - 1;
            const float4* xs = (const float4*)(X + (size_t)gr * 128 + seg * 32);
#pragma unroll
            for (int i = 0; i < 8; ++i) fa[i] = xs[i];
        }

        f32x4 acc[8];
#pragma unroll
        for (int tt = 0; tt < 8; ++tt) acc[tt] = (f32x4){0.f, 0.f, 0.f, 0.f};
        mfma_tile_compute(AsB, BtB, wv, ln, acc);
        __syncthreads();                 // AsB reads done

        // epilogue: bias+bf16 -> AsB padded rows (136 ushort = 272B stride)
#pragma unroll
        for (int tt = 0; tt < 8; ++tt) {
            const int n = tt * 16 + (ln & 15);
#pragma unroll
            for (int r2 = 0; r2 < 4; ++r2) {
                const int m = wv * 16 + ((ln >> 4) << 2) + r2;
                ((ushort*)AsB)[m * 136 + n] = (ushort)bf16r(acc[tt][r2] + bv[tt]);
            }
        }
        __syncthreads();

        // coalesced store AsB -> Pb
        {
            const int gr = s * 64 + r;
            if (gr < M) {
                uint4* dstp = (uint4*)Pb + (size_t)gr * 64 + grp * 16 + seg * 4;
#pragma unroll
                for (int i = 0; i < 4; ++i)
                    dstp[i] = *(const uint4*)(AsB + r * 272 + (seg * 4 + i) * 16);
            }
        }
    }
}

// ---------------------------------------------------------------------------
// K2a/b/c: hierarchical exclusive scan of hi32(packed_in) -> off_in.
// ---------------------------------------------------------------------------
__global__ __launch_bounds__(256)
void scan_p1(const ull* __restrict__ packed_in, int* __restrict__ bsum, int M)
{
    __shared__ int s[256];
    const int t = threadIdx.x;
    const int i = blockIdx.x * 256 + t;
    s[t] = (i < M) ? (int)(packed_in[i] >> 32) : 0;
    __syncthreads();
#pragma unroll
    for (int o = 128; o; o >>= 1) {
        if (t < o) s[t] += s[t + o];
        __syncthreads();
    }
    if (t == 0) bsum[blockIdx.x] = s[0];
}

__global__ __launch_bounds__(1024)
void scan_p2(int* __restrict__ bsum, int NB)
{
    __shared__ int s[1024];
    const int t = threadIdx.x;
    const int v = (t < NB) ? bsum[t] : 0;
    s[t] = v;
    __syncthreads();
    for (int o = 1; o < 1024; o <<= 1) {
        const int u = (t >= o) ? s[t - o] : 0;
        __syncthreads();
        s[t] += u;
        __syncthreads();
    }
    if (t < NB) bsum[t] = s[t] - v;   // exclusive
}

__global__ __launch_bounds__(256)
void scan_p3(const ull* __restrict__ packed_in, const int* __restrict__ bsum,
             int* __restrict__ off_in, int M)
{
    __shared__ int s[256];
    const int t = threadIdx.x;
    const int i = blockIdx.x * 256 + t;
    const int v = (i < M) ? (int)(packed_in[i] >> 32) : 0;
    s[t] = v;
    __syncthreads();
    for (int o = 1; o < 256; o <<= 1) {
        const int u = (t >= o) ? s[t - o] : 0;
        __syncthreads();
        s[t] += u;
        __syncthreads();
    }
    if (i < M) off_in[i] = bsum[blockIdx.x] + s[t] - v;
}

// ---------------------------------------------------------------------------
// K3: edge_out — 1 wave per src node (sorted-src run). a[v] in registers;
//     SOFTWARE-PIPELINED: iteration j+4's dst/counts/bb/p_ds prefetched
//     before computing iteration j (hides ~400cy gather latency under the
//     ~80-op lcs/accum ALU work). Fast sigmoid via __expf.
// ---------------------------------------------------------------------------
__global__ __launch_bounds__(THREADS)
void edge_out(const ushort* __restrict__ Pb, ushort* __restrict__ Hout,
              const int* __restrict__ dst, const float* __restrict__ counts,
              const float* __restrict__ W_l2, const float* __restrict__ b_l2,
              const int* __restrict__ off_out,
              const int* __restrict__ off_in, int* __restrict__ cur_in,
              float2* __restrict__ uw_in, int M)
{
    const int lane = threadIdx.x & 63;
    const int wid  = threadIdx.x >> 6;
    const int v    = blockIdx.x * 4 + wid;
    if (v >= M) return;
    const int g  = lane >> 4;       // edge group 0..3
    const int gl = lane & 15;       // 8 elems per lane

    const uint* rs = (const uint*)Pb + (size_t)v * 256;
    const uint4 av = ((const uint4*)(rs + 128))[gl];       // a[v], elems 256..383
    const float4 wa = ((const float4*)W_l2)[gl * 2];
    const float4 wb = ((const float4*)W_l2)[gl * 2 + 1];
    const float bl2 = b_l2[0];

    const int base = off_out[v];
    const int end  = off_out[v + 1];

    float a0 = 0.f, a1 = 0.f, a2 = 0.f, a3 = 0.f;
    float a4 = 0.f, a5 = 0.f, a6 = 0.f, a7 = 0.f;
    float dg = 0.f;

    int j = base + g;
    int   d0 = 0;  float c0 = 0.f;
    uint4 bv0 = {0, 0, 0, 0}, pv0 = {0, 0, 0, 0};
    if (j < end) {
        d0 = dst[j]; c0 = counts[j];
        const uint* rd = (const uint*)Pb + (size_t)d0 * 256;
        bv0 = ((const uint4*)(rd + 192))[gl];
        pv0 = ((const uint4*)(rd + 64))[gl];
    }

    for (; j < end; j += 4) {
        // ---- prefetch iteration j+4 (clamped; unused past end) ----
        const int jn = j + 4;
        const int jc = (jn < end) ? jn : j;
        const int   d1 = dst[jc];
        const float c1 = counts[jc];
        const uint* rdn = (const uint*)Pb + (size_t)d1 * 256;
        const uint4 bv1 = ((const uint4*)(rdn + 192))[gl];
        const uint4 pv1 = ((const uint4*)(rdn + 64))[gl];

        // ---- compute with iteration j's data ----
        float part =
            fmaxf(blo(av.x) + blo(bv0.x), 0.f) * wa.x + fmaxf(bhi(av.x) + bhi(bv0.x), 0.f) * wa.y +
            fmaxf(blo(av.y) + blo(bv0.y), 0.f) * wa.z + fmaxf(bhi(av.y) + bhi(bv0.y), 0.f) * wa.w +
            fmaxf(blo(av.z) + blo(bv0.z), 0.f) * wb.x + fmaxf(bhi(av.z) + bhi(bv0.z), 0.f) * wb.y +
            fmaxf(blo(av.w) + blo(bv0.w), 0.f) * wb.z + fmaxf(bhi(av.w) + bhi(bv0.w), 0.f) * wb.w;
        part += __shfl_xor(part, 1);
        part += __shfl_xor(part, 2);
        part += __shfl_xor(part, 4);
        part += __shfl_xor(part, 8);

        const float w = c0 / (1.f + __expf(-(part + bl2)));

        a0 = fmaf(blo(pv0.x), w, a0); a1 = fmaf(bhi(pv0.x), w, a1);
        a2 = fmaf(blo(pv0.y), w, a2); a3 = fmaf(bhi(pv0.y), w, a3);
        a4 = fmaf(blo(pv0.z), w, a4); a5 = fmaf(bhi(pv0.z), w, a5);
        a6 = fmaf(blo(pv0.w), w, a6); a7 = fmaf(bhi(pv0.w), w, a7);
        dg += c0;

        if (gl == 0) {
            const int r1 = atomicAdd(cur_in + d0, 1);
            uw_in[off_in[d0] + r1] = make_float2(__int_as_float(v), w);
        }

        d0 = d1; c0 = c1; bv0 = bv1; pv0 = pv1;
    }

#define RED2(a) a += __shfl_xor(a, 16); a += __shfl_xor(a, 32);
    RED2(a0) RED2(a1) RED2(a2) RED2(a3) RED2(a4) RED2(a5) RED2(a6) RED2(a7) RED2(dg)
#undef RED2

    if (g == 0) {
        const float r = 1.f / fmaxf(dg, 1.f);
        uint4 o;
        o.x = packbf(a0 * r, a1 * r);
        o.y = packbf(a2 * r, a3 * r);
        o.z = packbf(a4 * r, a5 * r);
        o.w = packbf(a6 * r, a7 * r);
        ((uint4*)((uint*)Hout + (size_t)v * 64))[gl] = o;
    }
}

// ---------------------------------------------------------------------------
// K4: agg_in — 1 wave per node, software-pipelined uw/p_sd gather.
//     Writes h_in -> Pb elems 256..383 (a dead after edge_out).
// ---------------------------------------------------------------------------
__global__ __launch_bounds__(THREADS)
void agg_in(ushort* __restrict__ Pb,
            const float2* __restrict__ uw_in,
            const int* __restrict__ off_in, const ull* __restrict__ packed_in,
            int M)
{
    const int lane = threadIdx.x & 63;
    const int wid  = threadIdx.x >> 6;
    const int v    = blockIdx.x * 4 + wid;
    if (v >= M) return;
    const int g  = lane >> 4;
    const int gl = lane & 15;

    const ull pk = packed_in[v];
    const int n  = (int)(pk >> 32);
    const float dg = (float)(uint)(pk & 0xffffffffu);
    const float2* __restrict__ uw = uw_in + off_in[v];

    float a0 = 0.f, a1 = 0.f, a2 = 0.f, a3 = 0.f;
    float a4 = 0.f, a5 = 0.f, a6 = 0.f, a7 = 0.f;

    int j = g;
    float2 p0 = make_float2(0.f, 0.f);
    uint4  pv0 = {0, 0, 0, 0};
    if (j < n) {
        p0 = uw[j];
        pv0 = ((const uint4*)((const uint*)Pb + (size_t)__float_as_int(p0.x) * 256))[gl];
    }

    for (; j < n; j += 4) {
        const int jn = j + 4;
        const int jc = (jn < n) ? jn : j;
        const float2 p1 = uw[jc];
        const uint4  pv1 = ((const uint4*)((const uint*)Pb + (size_t)__float_as_int(p1.x) * 256))[gl];

        const float w = p0.y;
        a0 = fmaf(blo(pv0.x), w, a0); a1 = fmaf(bhi(pv0.x), w, a1);
        a2 = fmaf(blo(pv0.y), w, a2); a3 = fmaf(bhi(pv0.y), w, a3);
        a4 = fmaf(blo(pv0.z), w, a4); a5 = fmaf(bhi(pv0.z), w, a5);
        a6 = fmaf(blo(pv0.w), w, a6); a7 = fmaf(bhi(pv0.w), w, a7);

        p0 = p1; pv0 = pv1;
    }
#define RED2(a) a += __shfl_xor(a, 16); a += __shfl_xor(a, 32);
    RED2(a0) RED2(a1) RED2(a2) RED2(a3) RED2(a4) RED2(a5) RED2(a6) RED2(a7)
#undef RED2

    if (g == 0) {
        const float r = 1.f / fmaxf(dg, 1.f);
        uint4 o;
        o.x = packbf(a0 * r, a1 * r);
        o.y = packbf(a2 * r, a3 * r);
        o.z = packbf(a4 * r, a5 * r);
        o.w = packbf(a6 * r, a7 * r);
        ((uint4*)((uint*)Pb + (size_t)v * 256 + 128))[gl] = o;
    }
}

// ---------------------------------------------------------------------------
// K5: gate_final (MFMA + fused finalize) — G = relu([h_in|h_out]@W_g1+b_g1)
//     stays in LDS; gate = sigmoid(G·W_g2+b_g2);
//     out = gate*h_in + (1-gate)*h_out + x.
// ---------------------------------------------------------------------------
__global__ __launch_bounds__(THREADS)
void gate_final(const ushort* __restrict__ Pb, const ushort* __restrict__ Hout,
                int M,
                const ushort* __restrict__ Wtg1, const float* __restrict__ b_g1,
                const float* __restrict__ W_g2, const float* __restrict__ b_g2,
                const float* __restrict__ x, float* __restrict__ out)
{
    __shared__ __align__(16) char AsB[16384];
    __shared__ __align__(16) char BtB[32768];

    const int tid = threadIdx.x;
    const int m0  = blockIdx.x * 64;
    const int wv = tid >> 6, ln = tid & 63;

    f32x4 acc[8];
#pragma unroll
    for (int tt = 0; tt < 8; ++tt) acc[tt] = (f32x4){0.f, 0.f, 0.f, 0.f};

    for (int h = 0; h < 2; ++h) {
        if (h) __syncthreads();
        // stage A half: h==0 -> h_in (Pb uint4 32..47), h==1 -> Hout row
        {
            const int r = tid >> 2, seg = tid & 3;
            int gr = m0 + r; if (gr >= M) gr = M - 1;
            const uint4* ps = (h == 0)
                ? ((const uint4*)Pb + (size_t)gr * 64 + 32 + seg * 4)
                : ((const uint4*)Hout + (size_t)gr * 16 + seg * 4);
#pragma unroll
            for (int i = 0; i < 4; ++i) {
                const uint4 u = ps[i];
                const int kbyte = seg * 64 + i * 16;
                *(uint4*)(AsB + r * 256 + (kbyte ^ ((r & 7) << 4))) = u;
            }
        }
        // stage Bt half from Wtg1 [128n][256k]
        {
            const int rn = tid >> 1, sg = tid & 1;
            const uint4* ws = (const uint4*)Wtg1 + (size_t)rn * 32 + h * 16 + sg * 8;
#pragma unroll
            for (int i = 0; i < 8; ++i) {
                const uint4 u = ws[i];
                const int kbyte = sg * 128 + i * 16;
                *(uint4*)(BtB + rn * 256 + (kbyte ^ ((rn & 7) << 4))) = u;
            }
        }
        __syncthreads();
        mfma_tile_compute(AsB, BtB, wv, ln, acc);
    }

    __syncthreads();                           // BtB reads done; reuse padded
    // G (relu'd) -> BtB padded rows (68 uints), packed uint writes
#pragma unroll
    for (int tt = 0; tt < 8; ++tt) {
        const int n = tt * 16 + (ln & 15);
        const float bv = b_g1[n];
#pragma unroll
        for (int r = 0; r < 4; ++r) {
            const int m = wv * 16 + ((ln >> 4) << 2) + r;
            const float val = fmaxf(acc[tt][r] + bv, 0.f);
            const float pr  = __shfl_xor(val, 1);
            if ((ln & 1) == 0)
                ((uint*)BtB)[m * 68 + (n >> 1)] = packbf(val, pr);
        }
    }
    __syncthreads();

    // fused finalize: wave wv handles rows wv*16 .. +15
    const float bg2 = b_g2[0];
    const float2 w2 = ((const float2*)W_g2)[ln];
#pragma unroll 4
    for (int r = 0; r < 16; ++r) {
        const int row = wv * 16 + r;
        const int gr  = m0 + row;
        const uint gv = ((const uint*)BtB)[row * 68 + ln];
        float part = blo(gv) * w2.x + bhi(gv) * w2.y;
#pragma unroll
        for (int off = 32; off; off >>= 1) part += __shfl_xor(part, off);
        const float gate = 1.f / (1.f + __expf(-(part + bg2)));
        if (gr < M) {
            const uint hin = ((const uint*)Pb)[(size_t)gr * 256 + 128 + ln];
            const uint hov = ((const uint*)Hout)[(size_t)gr * 64 + ln];
            const float2 xv = ((const float2*)x)[(size_t)gr * 64 + ln];
            float2 o;
            o.x = gate * blo(hin) + (1.f - gate) * blo(hov) + xv.x;
            o.y = gate * bhi(hin) + (1.f - gate) * bhi(hov) + xv.y;
            ((float2*)out)[(size_t)gr * 64 + ln] = o;
        }
    }
}

// ---------------------------------------------------------------------------
extern "C" void kernel_launch(void* const* d_in, const int* in_sizes, int n_in,
                              void* d_out, int out_size, void* d_ws, size_t ws_size,
                              hipStream_t stream)
{
    const float* x     = (const float*)d_in[0];
    const int*   src   = (const int*)  d_in[1];
    const int*   dst   = (const int*)  d_in[2];
    const float* cnts  = (const float*)d_in[3];
    const float* W_sd  = (const float*)d_in[4];
    const float* b_sd  = (const float*)d_in[5];
    const float* W_ds  = (const float*)d_in[6];
    const float* b_ds  = (const float*)d_in[7];
    const float* W_l1  = (const float*)d_in[8];
    const float* b_l1  = (const float*)d_in[9];
    const float* W_l2  = (const float*)d_in[10];
    const float* b_l2  = (const float*)d_in[11];
    const float* W_g1  = (const float*)d_in[12];
    const float* b_g1  = (const float*)d_in[13];
    const float* W_g2  = (const float*)d_in[14];
    const float* b_g2  = (const float*)d_in[15];

    const int M = in_sizes[0] / 128;
    const int E = in_sizes[1];

    // workspace:
    //   Pb        : M*512 bf16   (p_sd | p_ds | a->h_in | bb)
    //   Wt        : 4*128*128 bf16
    //   Wtg1      : 128*256 bf16
    //   Hout      : M*128 bf16   (normalized h_out)
    //   packed_in : ull[M] (zeroed)   cnt<<32 | int(deg)
    //   cur_in    : int[M] (zeroed)
    //   uw_in     : float2[E]
    //   off_in    : int[M]
    //   off_out   : int[M+1]
    //   bsum      : int[(M+255)/256]
    ushort* Pb        = (ushort*)d_ws;
    ushort* Wt        = Pb + (size_t)M * 512;
    ushort* Wtg1      = Wt + 4 * 16384;
    ushort* Hout      = Wtg1 + 32768;
    ull*    packed_in = (ull*)(Hout + (size_t)M * 128);
    int*    cur_in    = (int*)(packed_in + M);
    float2* uw_in     = (float2*)(cur_in + M);
    int*    off_in    = (int*)(uw_in + E);
    int*    off_out   = off_in + M;
    int*    bsum      = off_out + M + 1;

    // zero packed_in + cur_in (contiguous 12*M bytes)
    hipMemsetAsync(packed_in, 0, 12 * (size_t)M, stream);

    transpose_w<<<dim3(16, 6), THREADS, 0, stream>>>(W_sd, W_ds, W_l1, W_g1, Wt, Wtg1);

    const int ST  = (M + 63) / 64;      // 782 strips
    const int BPG = (ST + 3) / 4;       // 196 strip-sets per group
    gemm_node_count<<<NC + 4 * BPG, THREADS, 0, stream>>>(
        x, M, Wt, b_sd, b_ds, b_l1, Pb, src, dst, cnts, packed_in, off_out,
        E, ST, BPG);

    const int NB = (M + 255) / 256;     // 196 (must be <= 1024)
    scan_p1<<<NB, 256, 0, stream>>>(packed_in, bsum, M);
    scan_p2<<<1, 1024, 0, stream>>>(bsum, NB);
    scan_p3<<<NB, 256, 0, stream>>>(packed_in, bsum, off_in, M);

    edge_out<<<(M + 3) / 4, THREADS, 0, stream>>>(
        Pb, Hout, dst, cnts, W_l2, b_l2, off_out, off_in, cur_in, uw_in, M);

    agg_in<<<(M + 3) / 4, THREADS, 0, stream>>>(Pb, uw_in, off_in, packed_in, M);

    gate_final<<<(M + 63) / 64, THREADS, 0, stream>>>(Pb, Hout, M, Wtg1, b_g1,
                                                      W_g2, b_g2, x, (float*)d_out);
}

// Round 13
// 179.007 us; speedup vs baseline: 1.1182x; 1.0179x over previous
//
#include <hip/hip_runtime.h>
#include <math.h>

typedef unsigned int uint;
typedef unsigned long long ull;

#define THREADS 256
#define NC 96          // counting blocks at head of fused grid

typedef __attribute__((ext_vector_type(8))) short bf16x8;
typedef __attribute__((ext_vector_type(4))) float f32x4;

// ---- bf16 helpers (storage-only; math in fp32 / MFMA-fp32-accum) ----------
__device__ __forceinline__ float blo(uint u) { return __uint_as_float(u << 16); }
__device__ __forceinline__ float bhi(uint u) { return __uint_as_float(u & 0xffff0000u); }
__device__ __forceinline__ uint  bf16r(float x) {           // RTNE
    uint u = __float_as_uint(x);
    return (u + 0x7fffu + ((u >> 16) & 1u)) >> 16;
}
__device__ __forceinline__ uint packbf(float lo, float hi) {
    return bf16r(lo) | (bf16r(hi) << 16);
}

// ---------------------------------------------------------------------------
// K0: transpose weights to bf16 Wt[n][k] once.
// ---------------------------------------------------------------------------
__global__ __launch_bounds__(THREADS)
void transpose_w(const float* __restrict__ W_sd, const float* __restrict__ W_ds,
                 const float* __restrict__ W_l1, const float* __restrict__ W_g1,
                 ushort* __restrict__ Wt, ushort* __restrict__ Wtg1)
{
    __shared__ float tile[32][33];
    const int y = blockIdx.y;
    const float* src;
    ushort* dst;
    int dstK, kofs;
    if (y < 4) {
        src = (y == 0) ? W_sd : (y == 1) ? W_ds : (y == 2) ? W_l1 : (W_l1 + 16384);
        dst = Wt + y * 16384; dstK = 128; kofs = 0;
    } else {
        src = W_g1 + (y - 4) * 16384;
        dst = Wtg1; dstK = 256; kofs = (y - 4) * 128;
    }
    const int tix = blockIdx.x;
    const int k0 = (tix & 3) * 32, n0 = (tix >> 2) * 32;
    const int t = threadIdx.x;

    {
        const int r = t >> 3, c8 = t & 7;
        const float4 f = *(const float4*)(src + (size_t)(k0 + r) * 128 + n0 + c8 * 4);
        tile[r][c8 * 4 + 0] = f.x; tile[r][c8 * 4 + 1] = f.y;
        tile[r][c8 * 4 + 2] = f.z; tile[r][c8 * 4 + 3] = f.w;
    }
    __syncthreads();
    {
        const int n = t >> 3, k8 = t & 7;
        const float v0 = tile[k8 * 4 + 0][n], v1 = tile[k8 * 4 + 1][n];
        const float v2 = tile[k8 * 4 + 2][n], v3 = tile[k8 * 4 + 3][n];
        uint2 o; o.x = packbf(v0, v1); o.y = packbf(v2, v3);
        *(uint2*)(dst + (size_t)(n0 + n) * dstK + kofs + k0 + k8 * 4) = o;
    }
}

// ---------------------------------------------------------------------------
// K1 (fused, 1D grid = NC + NG, NG = 4*BPG):
//   bid < NC  -> edge counting (1 packed atomic/edge on dst) + off_out fill
//                from SORTED src. Grid-stride.
//   bid >= NC -> weight-stationary MFMA GEMM, XCD-bijective remap:
//                bg = bid-NC; p = (bg&7)*(NG/8) + (bg>>3); grp = p&3,
//                sidx = p>>2  -> the 4 grp-blocks of one strip-set sit on
//                ONE XCD (bids 8 apart) -> X rows L2-shared.
//                Bt(grp) staged once in LDS; A-fragments loaded DIRECTLY
//                from global to regs (no LDS, no strip syncs); raw floats
//                of strip k+1 prefetched during strip k's MFMAs; epilogue
//                packed-uint direct stores (no LDS bounce).
// ---------------------------------------------------------------------------
__global__ __launch_bounds__(THREADS)
void gemm_node_count(const float* __restrict__ X, int M,
                     const ushort* __restrict__ Wt,
                     const float* __restrict__ b_sd, const float* __restrict__ b_ds,
                     const float* __restrict__ b_l1,
                     ushort* __restrict__ Pb,
                     const int* __restrict__ src, const int* __restrict__ dst,
                     const float* __restrict__ counts,
                     ull* __restrict__ packed_in, int* __restrict__ off_out,
                     int E, int ST, int NG)
{
    __shared__ __align__(16) char BtB[32768];

    const int tid = threadIdx.x;
    const int bid = blockIdx.x;

    if (bid < NC) {
        const int stride = NC * THREADS;
        for (int e = bid * THREADS + tid; e < E; e += stride) {
            const int  d = dst[e];
            const uint c = (uint)counts[e];
            atomicAdd(packed_in + d, (1ULL << 32) | (ull)c);
        }
        // off_out: first edge index with src >= v (src sorted non-decreasing)
        for (int e = bid * THREADS + tid; e < E; e += stride) {
            const int cur  = src[e];
            const int prev = (e == 0) ? -1 : src[e - 1];
            for (int v = prev + 1; v <= cur; ++v) off_out[v] = e;
            if (e == E - 1)
                for (int v = cur + 1; v <= M; ++v) off_out[v] = E;
        }
        return;
    }

    // ---- XCD-bijective remap (NG % 8 == 0 by construction) ----
    const int bg   = bid - NC;
    const int per  = NG >> 3;
    const int p    = (bg & 7) * per + (bg >> 3);
    if (p >= NG) return;
    const int grp  = p & 3;
    const int sidx = p >> 2;
    if (sidx * 4 >= ST) return;

    const int wv = tid >> 6, ln = tid & 63;

    // ---- stage Bt(grp) ONCE (128 n-rows x 128 k, bf16 from L2, swizzled) --
    {
        const int rn = tid >> 1, sg = tid & 1;
        const uint4* ws = (const uint4*)(Wt + grp * 16384 + (size_t)rn * 128 + sg * 64);
#pragma unroll
        for (int i = 0; i < 8; ++i) {
            const uint4 u = ws[i];
            const int kbyte = sg * 128 + i * 16;
            *(uint4*)(BtB + rn * 256 + (kbyte ^ ((rn & 7) << 4))) = u;
        }
    }
    __syncthreads();        // Bt visible; no further block syncs needed

    const float* bias = (grp == 0) ? b_sd : (grp == 1) ? b_ds
                      : (grp == 2) ? b_l1 : nullptr;
    float bv[8];
#pragma unroll
    for (int tt = 0; tt < 8; ++tt)
        bv[tt] = bias ? bias[tt * 16 + (ln & 15)] : 0.f;

    // A-fragment geometry: lane ln, frag kk holds
    //   X[row = wv*16 + (ln&15)][k = kk*32 + (ln>>4)*8 .. +8]
    const int rowA = wv * 16 + (ln & 15);
    const int kofs = (ln >> 4) * 8;

    float4 raw[8];
    {
        int gr = sidx * 4 * 64 + rowA; if (gr >= M) gr = M - 1;
        const float* xr = X + (size_t)gr * 128 + kofs;
#pragma unroll
        for (int kk = 0; kk < 4; ++kk) {
            raw[2 * kk]     = *(const float4*)(xr + kk * 32);
            raw[2 * kk + 1] = *(const float4*)(xr + kk * 32 + 4);
        }
    }

    for (int k = 0; k < 4; ++k) {
        const int s = sidx * 4 + k;
        if (s >= ST) break;

        // pack current strip's A-fragments
        bf16x8 af[4];
#pragma unroll
        for (int kk = 0; kk < 4; ++kk) {
            uint4 u;
            u.x = packbf(raw[2 * kk].x, raw[2 * kk].y);
            u.y = packbf(raw[2 * kk].z, raw[2 * kk].w);
            u.z = packbf(raw[2 * kk + 1].x, raw[2 * kk + 1].y);
            u.w = packbf(raw[2 * kk + 1].z, raw[2 * kk + 1].w);
            af[kk] = *reinterpret_cast<bf16x8*>(&u);
        }

        // prefetch next strip's raw floats (overlaps MFMAs below)
        if (k < 3 && s + 1 < ST) {
            int gr = (s + 1) * 64 + rowA; if (gr >= M) gr = M - 1;
            const float* xr = X + (size_t)gr * 128 + kofs;
#pragma unroll
            for (int kk = 0; kk < 4; ++kk) {
                raw[2 * kk]     = *(const float4*)(xr + kk * 32);
                raw[2 * kk + 1] = *(const float4*)(xr + kk * 32 + 4);
            }
        }

        // MFMA: acc[tt] over 8 column tiles, 4 k-steps
        f32x4 acc[8];
#pragma unroll
        for (int tt = 0; tt < 8; ++tt) acc[tt] = (f32x4){0.f, 0.f, 0.f, 0.f};
        const int kgb = (ln >> 4) * 16;
#pragma unroll
        for (int kk = 0; kk < 4; ++kk) {
            const int kbyte = kk * 64 + kgb;
#pragma unroll
            for (int tt = 0; tt < 8; ++tt) {
                const int nrow = tt * 16 + (ln & 15);
                const bf16x8 b = *(const bf16x8*)(BtB + nrow * 256 + (kbyte ^ ((nrow & 7) << 4)));
                acc[tt] = __builtin_amdgcn_mfma_f32_16x16x32_bf16(af[kk], b, acc[tt], 0, 0, 0);
            }
        }

        // epilogue: bias + bf16 pack (shfl pair) + direct uint stores
        // C layout: row = wv*16 + (ln>>4)*4 + r2, col = ln&15
#pragma unroll
        for (int tt = 0; tt < 8; ++tt) {
#pragma unroll
            for (int r2 = 0; r2 < 4; ++r2) {
                const float val = acc[tt][r2] + bv[tt];
                const float pr  = __shfl_xor(val, 1);
                const int gr = s * 64 + wv * 16 + ((ln >> 4) << 2) + r2;
                if ((ln & 1) == 0 && gr < M) {
                    uint* dstp = (uint*)Pb + (size_t)gr * 256 + grp * 64
                               + tt * 8 + ((ln & 15) >> 1);
                    *dstp = packbf(val, pr);
                }
            }
        }
    }
}

// ---------------------------------------------------------------------------
// K2a/b/c: hierarchical exclusive scan of hi32(packed_in) -> off_in.
// ---------------------------------------------------------------------------
__global__ __launch_bounds__(256)
void scan_p1(const ull* __restrict__ packed_in, int* __restrict__ bsum, int M)
{
    __shared__ int s[256];
    const int t = threadIdx.x;
    const int i = blockIdx.x * 256 + t;
    s[t] = (i < M) ? (int)(packed_in[i] >> 32) : 0;
    __syncthreads();
#pragma unroll
    for (int o = 128; o; o >>= 1) {
        if (t < o) s[t] += s[t + o];
        __syncthreads();
    }
    if (t == 0) bsum[blockIdx.x] = s[0];
}

__global__ __launch_bounds__(1024)
void scan_p2(int* __restrict__ bsum, int NB)
{
    __shared__ int s[1024];
    const int t = threadIdx.x;
    const int v = (t < NB) ? bsum[t] : 0;
    s[t] = v;
    __syncthreads();
    for (int o = 1; o < 1024; o <<= 1) {
        const int u = (t >= o) ? s[t - o] : 0;
        __syncthreads();
        s[t] += u;
        __syncthreads();
    }
    if (t < NB) bsum[t] = s[t] - v;   // exclusive
}

__global__ __launch_bounds__(256)
void scan_p3(const ull* __restrict__ packed_in, const int* __restrict__ bsum,
             int* __restrict__ off_in, int M)
{
    __shared__ int s[256];
    const int t = threadIdx.x;
    const int i = blockIdx.x * 256 + t;
    const int v = (i < M) ? (int)(packed_in[i] >> 32) : 0;
    s[t] = v;
    __syncthreads();
    for (int o = 1; o < 256; o <<= 1) {
        const int u = (t >= o) ? s[t - o] : 0;
        __syncthreads();
        s[t] += u;
        __syncthreads();
    }
    if (i < M) off_in[i] = bsum[blockIdx.x] + s[t] - v;
}

// ---------------------------------------------------------------------------
// K3: edge_out — 1 wave per src node (sorted-src run). a[v] in registers;
//     software-pipelined gather; fast sigmoid.
// ---------------------------------------------------------------------------
__global__ __launch_bounds__(THREADS)
void edge_out(const ushort* __restrict__ Pb, ushort* __restrict__ Hout,
              const int* __restrict__ dst, const float* __restrict__ counts,
              const float* __restrict__ W_l2, const float* __restrict__ b_l2,
              const int* __restrict__ off_out,
              const int* __restrict__ off_in, int* __restrict__ cur_in,
              float2* __restrict__ uw_in, int M)
{
    const int lane = threadIdx.x & 63;
    const int wid  = threadIdx.x >> 6;
    const int v    = blockIdx.x * 4 + wid;
    if (v >= M) return;
    const int g  = lane >> 4;       // edge group 0..3
    const int gl = lane & 15;       // 8 elems per lane

    const uint* rs = (const uint*)Pb + (size_t)v * 256;
    const uint4 av = ((const uint4*)(rs + 128))[gl];       // a[v], elems 256..383
    const float4 wa = ((const float4*)W_l2)[gl * 2];
    const float4 wb = ((const float4*)W_l2)[gl * 2 + 1];
    const float bl2 = b_l2[0];

    const int base = off_out[v];
    const int end  = off_out[v + 1];

    float a0 = 0.f, a1 = 0.f, a2 = 0.f, a3 = 0.f;
    float a4 = 0.f, a5 = 0.f, a6 = 0.f, a7 = 0.f;
    float dg = 0.f;

    int j = base + g;
    int   d0 = 0;  float c0 = 0.f;
    uint4 bv0 = {0, 0, 0, 0}, pv0 = {0, 0, 0, 0};
    if (j < end) {
        d0 = dst[j]; c0 = counts[j];
        const uint* rd = (const uint*)Pb + (size_t)d0 * 256;
        bv0 = ((const uint4*)(rd + 192))[gl];
        pv0 = ((const uint4*)(rd + 64))[gl];
    }

    for (; j < end; j += 4) {
        // ---- prefetch iteration j+4 (clamped; unused past end) ----
        const int jn = j + 4;
        const int jc = (jn < end) ? jn : j;
        const int   d1 = dst[jc];
        const float c1 = counts[jc];
        const uint* rdn = (const uint*)Pb + (size_t)d1 * 256;
        const uint4 bv1 = ((const uint4*)(rdn + 192))[gl];
        const uint4 pv1 = ((const uint4*)(rdn + 64))[gl];

        // ---- compute with iteration j's data ----
        float part =
            fmaxf(blo(av.x) + blo(bv0.x), 0.f) * wa.x + fmaxf(bhi(av.x) + bhi(bv0.x), 0.f) * wa.y +
            fmaxf(blo(av.y) + blo(bv0.y), 0.f) * wa.z + fmaxf(bhi(av.y) + bhi(bv0.y), 0.f) * wa.w +
            fmaxf(blo(av.z) + blo(bv0.z), 0.f) * wb.x + fmaxf(bhi(av.z) + bhi(bv0.z), 0.f) * wb.y +
            fmaxf(blo(av.w) + blo(bv0.w), 0.f) * wb.z + fmaxf(bhi(av.w) + bhi(bv0.w), 0.f) * wb.w;
        part += __shfl_xor(part, 1);
        part += __shfl_xor(part, 2);
        part += __shfl_xor(part, 4);
        part += __shfl_xor(part, 8);

        const float w = c0 / (1.f + __expf(-(part + bl2)));

        a0 = fmaf(blo(pv0.x), w, a0); a1 = fmaf(bhi(pv0.x), w, a1);
        a2 = fmaf(blo(pv0.y), w, a2); a3 = fmaf(bhi(pv0.y), w, a3);
        a4 = fmaf(blo(pv0.z), w, a4); a5 = fmaf(bhi(pv0.z), w, a5);
        a6 = fmaf(blo(pv0.w), w, a6); a7 = fmaf(bhi(pv0.w), w, a7);
        dg += c0;

        if (gl == 0) {
            const int r1 = atomicAdd(cur_in + d0, 1);
            uw_in[off_in[d0] + r1] = make_float2(__int_as_float(v), w);
        }

        d0 = d1; c0 = c1; bv0 = bv1; pv0 = pv1;
    }

#define RED2(a) a += __shfl_xor(a, 16); a += __shfl_xor(a, 32);
    RED2(a0) RED2(a1) RED2(a2) RED2(a3) RED2(a4) RED2(a5) RED2(a6) RED2(a7) RED2(dg)
#undef RED2

    if (g == 0) {
        const float r = 1.f / fmaxf(dg, 1.f);
        uint4 o;
        o.x = packbf(a0 * r, a1 * r);
        o.y = packbf(a2 * r, a3 * r);
        o.z = packbf(a4 * r, a5 * r);
        o.w = packbf(a6 * r, a7 * r);
        ((uint4*)((uint*)Hout + (size_t)v * 64))[gl] = o;
    }
}

// ---------------------------------------------------------------------------
// K4: agg_in — 1 wave per node, software-pipelined uw/p_sd gather.
//     Writes h_in -> Pb elems 256..383 (a dead after edge_out).
// ---------------------------------------------------------------------------
__global__ __launch_bounds__(THREADS)
void agg_in(ushort* __restrict__ Pb,
            const float2* __restrict__ uw_in,
            const int* __restrict__ off_in, const ull* __restrict__ packed_in,
            int M)
{
    const int lane = threadIdx.x & 63;
    const int wid  = threadIdx.x >> 6;
    const int v    = blockIdx.x * 4 + wid;
    if (v >= M) return;
    const int g  = lane >> 4;
    const int gl = lane & 15;

    const ull pk = packed_in[v];
    const int n  = (int)(pk >> 32);
    const float dg = (float)(uint)(pk & 0xffffffffu);
    const float2* __restrict__ uw = uw_in + off_in[v];

    float a0 = 0.f, a1 = 0.f, a2 = 0.f, a3 = 0.f;
    float a4 = 0.f, a5 = 0.f, a6 = 0.f, a7 = 0.f;

    int j = g;
    float2 p0 = make_float2(0.f, 0.f);
    uint4  pv0 = {0, 0, 0, 0};
    if (j < n) {
        p0 = uw[j];
        pv0 = ((const uint4*)((const uint*)Pb + (size_t)__float_as_int(p0.x) * 256))[gl];
    }

    for (; j < n; j += 4) {
        const int jn = j + 4;
        const int jc = (jn < n) ? jn : j;
        const float2 p1 = uw[jc];
        const uint4  pv1 = ((const uint4*)((const uint*)Pb + (size_t)__float_as_int(p1.x) * 256))[gl];

        const float w = p0.y;
        a0 = fmaf(blo(pv0.x), w, a0); a1 = fmaf(bhi(pv0.x), w, a1);
        a2 = fmaf(blo(pv0.y), w, a2); a3 = fmaf(bhi(pv0.y), w, a3);
        a4 = fmaf(blo(pv0.z), w, a4); a5 = fmaf(bhi(pv0.z), w, a5);
        a6 = fmaf(blo(pv0.w), w, a6); a7 = fmaf(bhi(pv0.w), w, a7);

        p0 = p1; pv0 = pv1;
    }
#define RED2(a) a += __shfl_xor(a, 16); a += __shfl_xor(a, 32);
    RED2(a0) RED2(a1) RED2(a2) RED2(a3) RED2(a4) RED2(a5) RED2(a6) RED2(a7)
#undef RED2

    if (g == 0) {
        const float r = 1.f / fmaxf(dg, 1.f);
        uint4 o;
        o.x = packbf(a0 * r, a1 * r);
        o.y = packbf(a2 * r, a3 * r);
        o.z = packbf(a4 * r, a5 * r);
        o.w = packbf(a6 * r, a7 * r);
        ((uint4*)((uint*)Pb + (size_t)v * 256 + 128))[gl] = o;
    }
}

// ---------------------------------------------------------------------------
// K5: gate_final (MFMA + fused finalize) — G = relu([h_in|h_out]@W_g1+b_g1)
//     stays in LDS; gate = sigmoid(G·W_g2+b_g2);
//     out = gate*h_in + (1-gate)*h_out + x.
// ---------------------------------------------------------------------------
__global__ __launch_bounds__(THREADS)
void gate_final(const ushort* __restrict__ Pb, const ushort* __restrict__ Hout,
                int M,
                const ushort* __restrict__ Wtg1, const float* __restrict__ b_g1,
                const float* __restrict__ W_g2, const float* __restrict__ b_g2,
                const float* __restrict__ x, float* __restrict__ out)
{
    __shared__ __align__(16) char AsB[16384];
    __shared__ __align__(16) char BtB[32768];

    const int tid = threadIdx.x;
    const int m0  = blockIdx.x * 64;
    const int wv = tid >> 6, ln = tid & 63;

    f32x4 acc[8];
#pragma unroll
    for (int tt = 0; tt < 8; ++tt) acc[tt] = (f32x4){0.f, 0.f, 0.f, 0.f};

    const int kgb = (ln >> 4) * 16;
    for (int h = 0; h < 2; ++h) {
        if (h) __syncthreads();
        // stage A half: h==0 -> h_in (Pb uint4 32..47), h==1 -> Hout row
        {
            const int r = tid >> 2, seg = tid & 3;
            int gr = m0 + r; if (gr >= M) gr = M - 1;
            const uint4* ps = (h == 0)
                ? ((const uint4*)Pb + (size_t)gr * 64 + 32 + seg * 4)
                : ((const uint4*)Hout + (size_t)gr * 16 + seg * 4);
#pragma unroll
            for (int i = 0; i < 4; ++i) {
                const uint4 u = ps[i];
                const int kbyte = seg * 64 + i * 16;
                *(uint4*)(AsB + r * 256 + (kbyte ^ ((r & 7) << 4))) = u;
            }
        }
        // stage Bt half from Wtg1 [128n][256k]
        {
            const int rn = tid >> 1, sg = tid & 1;
            const uint4* ws = (const uint4*)Wtg1 + (size_t)rn * 32 + h * 16 + sg * 8;
#pragma unroll
            for (int i = 0; i < 8; ++i) {
                const uint4 u = ws[i];
                const int kbyte = sg * 128 + i * 16;
                *(uint4*)(BtB + rn * 256 + (kbyte ^ ((rn & 7) << 4))) = u;
            }
        }
        __syncthreads();
        {
            const int mrow = wv * 16 + (ln & 15);
#pragma unroll
            for (int kk = 0; kk < 4; ++kk) {
                const int kbyte = kk * 64 + kgb;
                const bf16x8 a = *(const bf16x8*)(AsB + mrow * 256 + (kbyte ^ ((mrow & 7) << 4)));
#pragma unroll
                for (int tt = 0; tt < 8; ++tt) {
                    const int nrow = tt * 16 + (ln & 15);
                    const bf16x8 b = *(const bf16x8*)(BtB + nrow * 256 + (kbyte ^ ((nrow & 7) << 4)));
                    acc[tt] = __builtin_amdgcn_mfma_f32_16x16x32_bf16(a, b, acc[tt], 0, 0, 0);
                }
            }
        }
    }

    __syncthreads();                           // BtB reads done; reuse padded
    // G (relu'd) -> BtB padded rows (68 uints), packed uint writes
#pragma unroll
    for (int tt = 0; tt < 8; ++tt) {
        const int n = tt * 16 + (ln & 15);
        const float bv = b_g1[n];
#pragma unroll
        for (int r = 0; r < 4; ++r) {
            const int m = wv * 16 + ((ln >> 4) << 2) + r;
            const float val = fmaxf(acc[tt][r] + bv, 0.f);
            const float pr  = __shfl_xor(val, 1);
            if ((ln & 1) == 0)
                ((uint*)BtB)[m * 68 + (n >> 1)] = packbf(val, pr);
        }
    }
    __syncthreads();

    // fused finalize: wave wv handles rows wv*16 .. +15
    const float bg2 = b_g2[0];
    const float2 w2 = ((const float2*)W_g2)[ln];
#pragma unroll 4
    for (int r = 0; r < 16; ++r) {
        const int row = wv * 16 + r;
        const int gr  = m0 + row;
        const uint gv = ((const uint*)BtB)[row * 68 + ln];
        float part = blo(gv) * w2.x + bhi(gv) * w2.y;
#pragma unroll
        for (int off = 32; off; off >>= 1) part += __shfl_xor(part, off);
        const float gate = 1.f / (1.f + __expf(-(part + bg2)));
        if (gr < M) {
            const uint hin = ((const uint*)Pb)[(size_t)gr * 256 + 128 + ln];
            const uint hov = ((const uint*)Hout)[(size_t)gr * 64 + ln];
            const float2 xv = ((const float2*)x)[(size_t)gr * 64 + ln];
            float2 o;
            o.x = gate * blo(hin) + (1.f - gate) * blo(hov) + xv.x;
            o.y = gate * bhi(hin) + (1.f - gate) * bhi(hov) + xv.y;
            ((float2*)out)[(size_t)gr * 64 + ln] = o;
        }
    }
}

// ---------------------------------------------------------------------------
extern "C" void kernel_launch(void* const* d_in, const int* in_sizes, int n_in,
                              void* d_out, int out_size, void* d_ws, size_t ws_size,
                              hipStream_t stream)
{
    const float* x     = (const float*)d_in[0];
    const int*   src   = (const int*)  d_in[1];
    const int*   dst   = (const int*)  d_in[2];
    const float* cnts  = (const float*)d_in[3];
    const float* W_sd  = (const float*)d_in[4];
    const float* b_sd  = (const float*)d_in[5];
    const float* W_ds  = (const float*)d_in[6];
    const float* b_ds  = (const float*)d_in[7];
    const float* W_l1  = (const float*)d_in[8];
    const float* b_l1  = (const float*)d_in[9];
    const float* W_l2  = (const float*)d_in[10];
    const float* b_l2  = (const float*)d_in[11];
    const float* W_g1  = (const float*)d_in[12];
    const float* b_g1  = (const float*)d_in[13];
    const float* W_g2  = (const float*)d_in[14];
    const float* b_g2  = (const float*)d_in[15];

    const int M = in_sizes[0] / 128;
    const int E = in_sizes[1];

    // workspace layout (as R12)
    ushort* Pb        = (ushort*)d_ws;
    ushort* Wt        = Pb + (size_t)M * 512;
    ushort* Wtg1      = Wt + 4 * 16384;
    ushort* Hout      = Wtg1 + 32768;
    ull*    packed_in = (ull*)(Hout + (size_t)M * 128);
    int*    cur_in    = (int*)(packed_in + M);
    float2* uw_in     = (float2*)(cur_in + M);
    int*    off_in    = (int*)(uw_in + E);
    int*    off_out   = off_in + M;
    int*    bsum      = off_out + M + 1;

    // zero packed_in + cur_in (contiguous 12*M bytes)
    hipMemsetAsync(packed_in, 0, 12 * (size_t)M, stream);

    transpose_w<<<dim3(16, 6), THREADS, 0, stream>>>(W_sd, W_ds, W_l1, W_g1, Wt, Wtg1);

    const int ST  = (M + 63) / 64;          // 782 strips
    const int BPG = (ST + 3) / 4;           // 196 strip-sets
    int NG = 4 * BPG;                       // 784 GEMM blocks
    NG = ((NG + 7) / 8) * 8;                // multiple of 8 for bijective remap
    gemm_node_count<<<NC + NG, THREADS, 0, stream>>>(
        x, M, Wt, b_sd, b_ds, b_l1, Pb, src, dst, cnts, packed_in, off_out,
        E, ST, NG);

    const int NB = (M + 255) / 256;         // 196 (must be <= 1024)
    scan_p1<<<NB, 256, 0, stream>>>(packed_in, bsum, M);
    scan_p2<<<1, 1024, 0, stream>>>(bsum, NB);
    scan_p3<<<NB, 256, 0, stream>>>(packed_in, bsum, off_in, M);

    edge_out<<<(M + 3) / 4, THREADS, 0, stream>>>(
        Pb, Hout, dst, cnts, W_l2, b_l2, off_out, off_in, cur_in, uw_in, M);

    agg_in<<<(M + 3) / 4, THREADS, 0, stream>>>(Pb, uw_in, off_in, packed_in, M);

    gate_final<<<(M + 63) / 64, THREADS, 0, stream>>>(Pb, Hout, M, Wtg1, b_g1,
                                                      W_g2, b_g2, x, (float*)d_out);
}